// Round 3
// baseline (521.142 us; speedup 1.0000x reference)
//
#include <hip/hip_runtime.h>
#include <hip/hip_bf16.h>
#include <cstdint>

// ============================================================================
// MoE transformer layer, MI355X gfx950.
// Precision: upstream of the router (LN1, QKV, attention, WO, LN2, logits) is
// ~fp32 via split-bf16 MFMA (3-pass); expert GEMM is plain bf16.
// R3: attention LDS-read-bound fix — 32 q/wave (halves K/V LDS reads per
// FLOP), V pre-transposed once (vtrans), XOR-swizzled K/V/P LDS layouts,
// softmax scale folded into Q, wave-uniform masking.
// ============================================================================

typedef __bf16 bf16;
typedef __bf16 bf16x8 __attribute__((ext_vector_type(8)));
typedef float f32x4 __attribute__((ext_vector_type(4)));

#define MFMA(a, b, c) __builtin_amdgcn_mfma_f32_16x16x32_bf16(a, b, c, 0, 0, 0)

__device__ __forceinline__ void gld16(void* lds, const void* g) {
  __builtin_amdgcn_global_load_lds(
      (const __attribute__((address_space(1))) void*)g,
      (__attribute__((address_space(3))) void*)lds, 16, 0, 0);
}

// ---------------------------------------------------------------------------
__global__ void split_f32(const float* __restrict__ s, bf16* __restrict__ hi,
                          bf16* __restrict__ lo, int n) {
  int i = (blockIdx.x * 256 + threadIdx.x) * 4;
  if (i >= n) return;
  float4 v = *(const float4*)(s + i);
  float a[4] = {v.x, v.y, v.z, v.w};
#pragma unroll
  for (int j = 0; j < 4; j++) {
    bf16 h = (bf16)a[j];
    hi[i + j] = h;
    lo[i + j] = (bf16)(a[j] - (float)h);
  }
}

__global__ void cvt_f32(const float* __restrict__ s, bf16* __restrict__ hi, int n) {
  int i = (blockIdx.x * 256 + threadIdx.x) * 4;
  if (i >= n) return;
  float4 v = *(const float4*)(s + i);
  hi[i] = (bf16)v.x; hi[i + 1] = (bf16)v.y;
  hi[i + 2] = (bf16)v.z; hi[i + 3] = (bf16)v.w;
}

// ---------------------------------------------------------------------------
__global__ void ln_split(const float* __restrict__ x, const float* __restrict__ g,
                         const float* __restrict__ b, bf16* __restrict__ hi,
                         bf16* __restrict__ lo) {
  int tok = blockIdx.x, t = threadIdx.x;
  float4 v = ((const float4*)(x + (size_t)tok * 1024))[t];
  float s = v.x + v.y + v.z + v.w;
  float ss = v.x * v.x + v.y * v.y + v.z * v.z + v.w * v.w;
#pragma unroll
  for (int o = 1; o < 64; o <<= 1) { s += __shfl_xor(s, o); ss += __shfl_xor(ss, o); }
  __shared__ float red[8];
  int w = t >> 6, lane = t & 63;
  if (lane == 0) { red[w] = s; red[4 + w] = ss; }
  __syncthreads();
  s = red[0] + red[1] + red[2] + red[3];
  ss = red[4] + red[5] + red[6] + red[7];
  float mu = s * (1.f / 1024.f);
  float rstd = rsqrtf(ss * (1.f / 1024.f) - mu * mu + 1e-5f);
  float4 gv = ((const float4*)g)[t], bv = ((const float4*)b)[t];
  float y[4] = {(v.x - mu) * rstd * gv.x + bv.x, (v.y - mu) * rstd * gv.y + bv.y,
                (v.z - mu) * rstd * gv.z + bv.z, (v.w - mu) * rstd * gv.w + bv.w};
  size_t o = (size_t)tok * 1024 + t * 4;
#pragma unroll
  for (int j = 0; j < 4; j++) {
    bf16 h = (bf16)y[j];
    hi[o + j] = h;
    lo[o + j] = (bf16)(y[j] - (float)h);
  }
}

// ---------------------------------------------------------------------------
// Split-bf16 NT GEMM core: C(128x128 fp32) = (Ah+Al) @ (Bh+Bl)^T, K=1024.
// ---------------------------------------------------------------------------
__device__ __forceinline__ void gemm_core_split(
    const bf16* __restrict__ Ah, const bf16* __restrict__ Al,
    const bf16* __restrict__ Bh, const bf16* __restrict__ Bl, int m0, int n0,
    f32x4 (&acc)[4][4]) {
  __shared__ __align__(16) bf16 As_h[4096], As_l[4096], Bs_h[4096], Bs_l[4096];
  int t = threadIdx.x, lane = t & 63, w = t >> 6;
  int i0 = t, i1 = t + 256;
  const bf16* a0h = Ah + (size_t)(m0 + (i0 >> 2)) * 1024 + (i0 & 3) * 8;
  const bf16* a1h = Ah + (size_t)(m0 + (i1 >> 2)) * 1024 + (i1 & 3) * 8;
  const bf16* a0l = Al + (size_t)(m0 + (i0 >> 2)) * 1024 + (i0 & 3) * 8;
  const bf16* a1l = Al + (size_t)(m0 + (i1 >> 2)) * 1024 + (i1 & 3) * 8;
  const bf16* b0h = Bh + (size_t)(n0 + (i0 >> 2)) * 1024 + (i0 & 3) * 8;
  const bf16* b1h = Bh + (size_t)(n0 + (i1 >> 2)) * 1024 + (i1 & 3) * 8;
  const bf16* b0l = Bl + (size_t)(n0 + (i0 >> 2)) * 1024 + (i0 & 3) * 8;
  const bf16* b1l = Bl + (size_t)(n0 + (i1 >> 2)) * 1024 + (i1 & 3) * 8;
  int wm = (w >> 1) * 64, wn = (w & 1) * 64;
  int lr = lane & 15, lq = lane >> 4;
  for (int k0 = 0; k0 < 1024; k0 += 32) {
    __syncthreads();
    gld16(&As_h[i0 * 8], a0h + k0); gld16(&As_h[i1 * 8], a1h + k0);
    gld16(&As_l[i0 * 8], a0l + k0); gld16(&As_l[i1 * 8], a1l + k0);
    gld16(&Bs_h[i0 * 8], b0h + k0); gld16(&Bs_h[i1 * 8], b1h + k0);
    gld16(&Bs_l[i0 * 8], b0l + k0); gld16(&Bs_l[i1 * 8], b1l + k0);
    __syncthreads();
    bf16x8 ah[4], al4[4], bh[4], bl4[4];
#pragma unroll
    for (int i = 0; i < 4; i++) {
      ah[i]  = *(const bf16x8*)&As_h[(wm + i * 16 + lr) * 32 + lq * 8];
      al4[i] = *(const bf16x8*)&As_l[(wm + i * 16 + lr) * 32 + lq * 8];
      bh[i]  = *(const bf16x8*)&Bs_h[(wn + i * 16 + lr) * 32 + lq * 8];
      bl4[i] = *(const bf16x8*)&Bs_l[(wn + i * 16 + lr) * 32 + lq * 8];
    }
#pragma unroll
    for (int i = 0; i < 4; i++)
#pragma unroll
      for (int j = 0; j < 4; j++) {
        f32x4 c = acc[i][j];
        c = MFMA(ah[i], bh[j], c);
        c = MFMA(ah[i], bl4[j], c);
        c = MFMA(al4[i], bh[j], c);
        acc[i][j] = c;
      }
  }
}

// QKV projection. z==0 output (Q) is pre-scaled by 1/sqrt(hd)*log2(e) so the
// attention kernel's scores are already in the exp2 domain.
__global__ __launch_bounds__(256, 2) void gemm_qkv(
    const bf16* __restrict__ hh, const bf16* __restrict__ hl,
    const bf16* __restrict__ wqh, const bf16* __restrict__ wql,
    const bf16* __restrict__ wkh, const bf16* __restrict__ wkl,
    const bf16* __restrict__ wvh, const bf16* __restrict__ wvl,
    bf16* __restrict__ qh, bf16* __restrict__ ql, bf16* __restrict__ kh,
    bf16* __restrict__ kl, bf16* __restrict__ vh, bf16* __restrict__ vl) {
  int n0 = blockIdx.x * 128, m0 = blockIdx.y * 128, z = blockIdx.z;
  const bf16 *Bh = wqh, *Bl = wql;
  bf16 *Oh = qh, *Ol = ql;
  if (z == 1) { Bh = wkh; Bl = wkl; Oh = kh; Ol = kl; }
  if (z == 2) { Bh = wvh; Bl = wvl; Oh = vh; Ol = vl; }
  float scale = (z == 0) ? (0.125f * 1.44269504f) : 1.0f;
  f32x4 acc[4][4];
#pragma unroll
  for (int i = 0; i < 4; i++)
#pragma unroll
    for (int j = 0; j < 4; j++) acc[i][j] = (f32x4){0.f, 0.f, 0.f, 0.f};
  gemm_core_split(hh, hl, Bh, Bl, m0, n0, acc);
  int t = threadIdx.x, lane = t & 63, w = t >> 6;
  int wm = (w >> 1) * 64, wn = (w & 1) * 64, lr = lane & 15, lq = lane >> 4;
#pragma unroll
  for (int i = 0; i < 4; i++)
#pragma unroll
    for (int j = 0; j < 4; j++)
#pragma unroll
      for (int r = 0; r < 4; r++) {
        size_t row = m0 + wm + i * 16 + lq * 4 + r;
        int col = n0 + wn + j * 16 + lr;
        float v = acc[i][j][r] * scale;
        bf16 h = (bf16)v;
        Oh[row * 1024 + col] = h;
        Ol[row * 1024 + col] = (bf16)(v - (float)h);
      }
}

// WO projection + residual: out_f32 = x + attn @ wo^T
__global__ __launch_bounds__(256, 2) void gemm_wo(
    const bf16* __restrict__ ah, const bf16* __restrict__ al,
    const bf16* __restrict__ bh, const bf16* __restrict__ bl,
    const float* __restrict__ resid, float* __restrict__ outp) {
  int n0 = blockIdx.x * 128, m0 = blockIdx.y * 128;
  f32x4 acc[4][4];
#pragma unroll
  for (int i = 0; i < 4; i++)
#pragma unroll
    for (int j = 0; j < 4; j++) acc[i][j] = (f32x4){0.f, 0.f, 0.f, 0.f};
  gemm_core_split(ah, al, bh, bl, m0, n0, acc);
  int t = threadIdx.x, lane = t & 63, w = t >> 6;
  int wm = (w >> 1) * 64, wn = (w & 1) * 64, lr = lane & 15, lq = lane >> 4;
#pragma unroll
  for (int i = 0; i < 4; i++)
#pragma unroll
    for (int j = 0; j < 4; j++)
#pragma unroll
      for (int r = 0; r < 4; r++) {
        size_t row = m0 + wm + i * 16 + lq * 4 + r;
        int col = n0 + wn + j * 16 + lr;
        outp[row * 1024 + col] = resid[row * 1024 + col] + acc[i][j][r];
      }
}

// ---------------------------------------------------------------------------
// V transpose: V[b*2048+s][head*64+d] -> Vt[(b*16+head)*64+d][s] (per buffer).
// LDS-tiled 64x64 with XOR swizzle (write free, read ideal).
// ---------------------------------------------------------------------------
__global__ void vtrans(const bf16* __restrict__ vh, const bf16* __restrict__ vl,
                       bf16* __restrict__ vth, bf16* __restrict__ vtl) {
  int bh = blockIdx.y, s0 = blockIdx.x * 64;
  int b = bh >> 4, h = bh & 15;
  int t = threadIdx.x;
  __shared__ __align__(16) bf16 tile[4096];
  int r = t >> 2, c4 = t & 3;      // load: token row r, 16-col group c4
  int dr = t >> 2, tg = t & 3;     // store: d row dr, 16-token group tg
#pragma unroll
  for (int pass = 0; pass < 2; pass++) {
    const bf16* src = pass ? vl : vh;
    bf16* dst = pass ? vtl : vth;
    if (pass) __syncthreads();
    const bf16* sp = src + (size_t)(b * 2048 + s0 + r) * 1024 + h * 64 + c4 * 16;
    bf16x8 v0 = *(const bf16x8*)sp;
    bf16x8 v1 = *(const bf16x8*)(sp + 8);
#pragma unroll
    for (int j = 0; j < 8; j++) {
      int d0 = c4 * 16 + j, d1 = c4 * 16 + 8 + j;
      tile[d0 * 64 + (r ^ ((d0 >> 3) << 3))] = v0[j];
      tile[d1 * 64 + (r ^ ((d1 >> 3) << 3))] = v1[j];
    }
    __syncthreads();
#pragma unroll
    for (int hf = 0; hf < 2; hf++) {
      int tok = tg * 16 + hf * 8;
      bf16x8 o = *(const bf16x8*)&tile[dr * 64 + (tok ^ ((dr >> 3) << 3))];
      *(bf16x8*)(dst + (size_t)(bh * 64 + dr) * 2048 + s0 + tok) = o;
    }
  }
}

// ---------------------------------------------------------------------------
// Flash attention, split-bf16, no running max (scores bounded; Q pre-scaled
// into exp2 domain). Block = 128 queries x 1 head, 4 waves x 32 queries.
// 64-key tiles; K and Vt staged via gld16 with XOR group swizzle
// (phys group = g ^ (row&7)); P LDS round-trip per 32-key half.
// ---------------------------------------------------------------------------
__global__ __launch_bounds__(256, 2) void attn_fused(
    const bf16* __restrict__ qh, const bf16* __restrict__ ql,
    const bf16* __restrict__ kh, const bf16* __restrict__ kl,
    const bf16* __restrict__ vth, const bf16* __restrict__ vtl,
    bf16* __restrict__ oh, bf16* __restrict__ ol) {
  const int S = 2048, D = 1024;
  int qt = 15 - blockIdx.y;            // heavy q-tiles first
  int hb = blockIdx.x;                 // b*16 + head
  int head = hb & 15, b = hb >> 4;
  int qb = qt * 128;
  int t = threadIdx.x, lane = t & 63, w = t >> 6;
  int lr = lane & 15, lq = lane >> 4;
  int base = b * S, hcol = head * 64;

  __shared__ __align__(16) bf16 Kh_s[4096], Kl_s[4096];   // [key64][d64] swz
  __shared__ __align__(16) bf16 Vh_s[4096], Vl_s[4096];   // [d64][key64] swz
  __shared__ __align__(16) bf16 Ph_s[4][1024], Pl_s[4][1024]; // [w][32q][32k] swz

  // Q fragments: wave covers queries qb + w*32 .. +31 (two 16-row groups)
  bf16x8 qfh[2][2], qfl[2][2];
#pragma unroll
  for (int qr = 0; qr < 2; qr++) {
    const bf16* p1 = qh + (size_t)(base + qb + w * 32 + qr * 16 + lr) * D + hcol + lq * 8;
    const bf16* p2 = ql + (size_t)(base + qb + w * 32 + qr * 16 + lr) * D + hcol + lq * 8;
    qfh[qr][0] = *(const bf16x8*)p1; qfh[qr][1] = *(const bf16x8*)(p1 + 32);
    qfl[qr][0] = *(const bf16x8*)p2; qfl[qr][1] = *(const bf16x8*)(p2 + 32);
  }
  f32x4 O[2][4];
  float lrow[2][4];
#pragma unroll
  for (int qr = 0; qr < 2; qr++)
#pragma unroll
    for (int j = 0; j < 4; j++) {
      O[qr][j] = (f32x4){0.f, 0.f, 0.f, 0.f};
      lrow[qr][j] = 0.f;
    }

  // staging slots: s in {t, t+256}; row = s>>3, phys group p = s&7,
  // data group g = p ^ (row&7)
  int r0 = t >> 3, p0 = t & 7;
  int r1 = (t + 256) >> 3, p1 = (t + 256) & 7;
  int g0 = p0 ^ (r0 & 7), g1 = p1 ^ (r1 & 7);
  const bf16* k0hp = kh + (size_t)(base + r0) * D + hcol + g0 * 8;
  const bf16* k1hp = kh + (size_t)(base + r1) * D + hcol + g1 * 8;
  const bf16* k0lp = kl + (size_t)(base + r0) * D + hcol + g0 * 8;
  const bf16* k1lp = kl + (size_t)(base + r1) * D + hcol + g1 * 8;
  const bf16* v0hp = vth + (size_t)(hb * 64 + r0) * 2048 + g0 * 8;
  const bf16* v1hp = vth + (size_t)(hb * 64 + r1) * 2048 + g1 * 8;
  const bf16* v0lp = vtl + (size_t)(hb * 64 + r0) * 2048 + g0 * 8;
  const bf16* v1lp = vtl + (size_t)(hb * 64 + r1) * 2048 + g1 * 8;

  int qwmin = qb + w * 32;           // wave's min query
  int pswz = ((lr >> 2) & 1) << 4;   // P read swizzle

  for (int kt = 0; kt <= qb + 64; kt += 64) {
    __syncthreads();
    gld16(&Kh_s[t * 8], k0hp + (size_t)kt * D);
    gld16(&Kh_s[2048 + t * 8], k1hp + (size_t)kt * D);
    gld16(&Kl_s[t * 8], k0lp + (size_t)kt * D);
    gld16(&Kl_s[2048 + t * 8], k1lp + (size_t)kt * D);
    gld16(&Vh_s[t * 8], v0hp + kt);
    gld16(&Vh_s[2048 + t * 8], v1hp + kt);
    gld16(&Vl_s[t * 8], v0lp + kt);
    gld16(&Vl_s[2048 + t * 8], v1lp + kt);
    __syncthreads();
    if (kt > qwmin + 31) continue;   // wave has no unmasked rows this tile
    bool need_mask = (kt + 63 > qwmin);
#pragma unroll
    for (int hf = 0; hf < 2; hf++) {
      // ---- QK^T for this 32-key half (2 key-subtiles of 16) ----
      f32x4 sc[2][2];
#pragma unroll
      for (int tt = 0; tt < 2; tt++) {
        int key16 = (hf * 2 + tt) * 16 + lr;
        int gl = (lq ^ (key16 & 7)) * 8;
        int gh = ((4 + lq) ^ (key16 & 7)) * 8;
        bf16x8 k0 = *(const bf16x8*)&Kh_s[key16 * 64 + gl];
        bf16x8 k1 = *(const bf16x8*)&Kh_s[key16 * 64 + gh];
        bf16x8 m0 = *(const bf16x8*)&Kl_s[key16 * 64 + gl];
        bf16x8 m1 = *(const bf16x8*)&Kl_s[key16 * 64 + gh];
#pragma unroll
        for (int qr = 0; qr < 2; qr++) {
          f32x4 s = (f32x4){0.f, 0.f, 0.f, 0.f};
          s = MFMA(qfh[qr][0], k0, s); s = MFMA(qfh[qr][1], k1, s);
          s = MFMA(qfh[qr][0], m0, s); s = MFMA(qfh[qr][1], m1, s);
          s = MFMA(qfl[qr][0], k0, s); s = MFMA(qfl[qr][1], k1, s);
          sc[qr][tt] = s;
        }
      }
      // ---- softmax (exp2, fixed shift), P split -> LDS ----
#pragma unroll
      for (int qr = 0; qr < 2; qr++)
#pragma unroll
        for (int tt = 0; tt < 2; tt++) {
          int key = kt + (hf * 2 + tt) * 16 + lr;
#pragma unroll
          for (int r = 0; r < 4; r++) {
            float s = sc[qr][tt][r];
            if (need_mask) {
              int q = qwmin + qr * 16 + lq * 4 + r;
              s = (key <= q) ? s : -30000.f;
            }
            float pv = __builtin_amdgcn_exp2f(s);
            lrow[qr][r] += pv;
            bf16 ph = (bf16)pv;
            int col = (tt * 16 + lr) ^ ((lq & 1) << 4);
            int idx = (qr * 16 + lq * 4 + r) * 32 + col;
            Ph_s[w][idx] = ph;
            Pl_s[w][idx] = (bf16)(pv - (float)ph);
          }
        }
      // ---- V fragments for this half (shared across qr) ----
      bf16x8 vbh[4], vbl[4];
#pragma unroll
      for (int j = 0; j < 4; j++) {
        int d = j * 16 + lr;
        int gv = ((hf * 4 + lq) ^ (d & 7)) * 8;
        vbh[j] = *(const bf16x8*)&Vh_s[d * 64 + gv];
        vbl[j] = *(const bf16x8*)&Vl_s[d * 64 + gv];
      }
      // ---- PV ----
#pragma unroll
      for (int qr = 0; qr < 2; qr++) {
        int poff = (qr * 16 + lr) * 32 + ((lq * 8) ^ pswz);
        bf16x8 pf = *(const bf16x8*)&Ph_s[w][poff];
        bf16x8 pl2 = *(const bf16x8*)&Pl_s[w][poff];
#pragma unroll
        for (int j = 0; j < 4; j++) {
          f32x4 c = O[qr][j];
          c = MFMA(pf, vbh[j], c);
          c = MFMA(pf, vbl[j], c);
          c = MFMA(pl2, vbh[j], c);
          O[qr][j] = c;
        }
      }
    }
  }
  // ---- epilogue ----
#pragma unroll
  for (int qr = 0; qr < 2; qr++) {
    float linv[4];
#pragma unroll
    for (int r = 0; r < 4; r++) {
      float l = lrow[qr][r];
      l += __shfl_xor(l, 1); l += __shfl_xor(l, 2);
      l += __shfl_xor(l, 4); l += __shfl_xor(l, 8);
      linv[r] = 1.f / l;
    }
#pragma unroll
    for (int j = 0; j < 4; j++)
#pragma unroll
      for (int r = 0; r < 4; r++) {
        size_t tok = (size_t)(base + qb + w * 32 + qr * 16 + lq * 4 + r);
        int col = hcol + j * 16 + lr;
        float v = O[qr][j][r] * linv[r];
        bf16 h = (bf16)v;
        oh[tok * D + col] = h;
        ol[tok * D + col] = (bf16)(v - (float)h);
      }
  }
}

// ---------------------------------------------------------------------------
// Router: fused LN2 + logits + top-2 + gates + per-expert list build.
// ---------------------------------------------------------------------------
__global__ void router_ln2(const float* __restrict__ x1, const float* __restrict__ g,
                           const float* __restrict__ b, const float* __restrict__ rw,
                           bf16* __restrict__ h2h, int* __restrict__ tlist,
                           float* __restrict__ glist, int* __restrict__ cursor) {
  int tok = blockIdx.x, t = threadIdx.x;
  float4 v = ((const float4*)(x1 + (size_t)tok * 1024))[t];
  float s = v.x + v.y + v.z + v.w;
  float ss = v.x * v.x + v.y * v.y + v.z * v.z + v.w * v.w;
#pragma unroll
  for (int o = 1; o < 64; o <<= 1) { s += __shfl_xor(s, o); ss += __shfl_xor(ss, o); }
  __shared__ float red[8];
  __shared__ float h2s[1024];
  __shared__ float lg[8];
  int w = t >> 6, lane = t & 63;
  if (lane == 0) { red[w] = s; red[4 + w] = ss; }
  __syncthreads();
  s = red[0] + red[1] + red[2] + red[3];
  ss = red[4] + red[5] + red[6] + red[7];
  float mu = s * (1.f / 1024.f);
  float rstd = rsqrtf(ss * (1.f / 1024.f) - mu * mu + 1e-5f);
  float4 gv = ((const float4*)g)[t], bv = ((const float4*)b)[t];
  float y[4] = {(v.x - mu) * rstd * gv.x + bv.x, (v.y - mu) * rstd * gv.y + bv.y,
                (v.z - mu) * rstd * gv.z + bv.z, (v.w - mu) * rstd * gv.w + bv.w};
  int o4 = t * 4;
#pragma unroll
  for (int j = 0; j < 4; j++) {
    h2s[o4 + j] = y[j];
    h2h[(size_t)tok * 1024 + o4 + j] = (bf16)y[j];
  }
  __syncthreads();
#pragma unroll
  for (int ee = 0; ee < 2; ee++) {
    int e = w * 2 + ee;
    float p = 0.f;
    for (int d = lane; d < 1024; d += 64) p += h2s[d] * rw[e * 1024 + d];
#pragma unroll
    for (int o = 1; o < 64; o <<= 1) p += __shfl_xor(p, o);
    if (lane == 0) lg[e] = p;
  }
  __syncthreads();
  if (t == 0) {
    int i0 = 0; float l0 = lg[0];
#pragma unroll
    for (int e = 1; e < 8; e++) if (lg[e] > l0) { l0 = lg[e]; i0 = e; }
    int i1 = -1; float l1 = -3e38f;
#pragma unroll
    for (int e = 0; e < 8; e++) if (e != i0 && lg[e] > l1) { l1 = lg[e]; i1 = e; }
    float e1 = expf(l1 - l0);
    float den = 1.f + e1;
    float g0 = 1.f / den, g1 = e1 / den;
    int s0 = atomicAdd(&cursor[i0], 1);
    tlist[i0 * 4096 + s0] = tok; glist[i0 * 4096 + s0] = g0;
    int s1 = atomicAdd(&cursor[i1], 1);
    tlist[i1 * 4096 + s1] = tok; glist[i1 * 4096 + s1] = g1;
  }
}

__global__ void init_lists(int* __restrict__ tlist, float* __restrict__ glist,
                           int* __restrict__ cursor) {
  int i = blockIdx.x * 256 + threadIdx.x;
  if (i < 32768) { tlist[i] = 0; glist[i] = 0.f; }
  if (i < 8) cursor[i] = 0;
}

// ---------------------------------------------------------------------------
// Routed expert GEMM (plain bf16): gather via tlist, atomicAdd scatter.
// ---------------------------------------------------------------------------
__global__ __launch_bounds__(256, 2) void gemm_moe(
    const bf16* __restrict__ A, const bf16* __restrict__ W,
    const int* __restrict__ tlist, const float* __restrict__ glist,
    const int* __restrict__ cnt, float* __restrict__ outp) {
  int e = blockIdx.z;
  int count = cnt[e];
  int m0 = blockIdx.y * 128;
  if (m0 >= count) return;
  int n0 = blockIdx.x * 128;
  const int* tl = tlist + e * 4096;
  const bf16* B = W + (size_t)e * 1024 * 1024;
  __shared__ __align__(16) bf16 As[4096], Bs[4096];
  int t = threadIdx.x, lane = t & 63, w = t >> 6;
  int i0 = t, i1 = t + 256;
  int ra = tl[m0 + (i0 >> 2)], rb = tl[m0 + (i1 >> 2)];
  const bf16* a0 = A + (size_t)ra * 1024 + (i0 & 3) * 8;
  const bf16* a1 = A + (size_t)rb * 1024 + (i1 & 3) * 8;
  const bf16* b0 = B + (size_t)(n0 + (i0 >> 2)) * 1024 + (i0 & 3) * 8;
  const bf16* b1 = B + (size_t)(n0 + (i1 >> 2)) * 1024 + (i1 & 3) * 8;
  int wm = (w >> 1) * 64, wn = (w & 1) * 64, lr = lane & 15, lq = lane >> 4;
  f32x4 acc[4][4];
#pragma unroll
  for (int i = 0; i < 4; i++)
#pragma unroll
    for (int j = 0; j < 4; j++) acc[i][j] = (f32x4){0.f, 0.f, 0.f, 0.f};
  for (int k0 = 0; k0 < 1024; k0 += 32) {
    __syncthreads();
    gld16(&As[i0 * 8], a0 + k0); gld16(&As[i1 * 8], a1 + k0);
    gld16(&Bs[i0 * 8], b0 + k0); gld16(&Bs[i1 * 8], b1 + k0);
    __syncthreads();
    bf16x8 af[4], bfr[4];
#pragma unroll
    for (int i = 0; i < 4; i++) {
      af[i] = *(const bf16x8*)&As[(wm + i * 16 + lr) * 32 + lq * 8];
      bfr[i] = *(const bf16x8*)&Bs[(wn + i * 16 + lr) * 32 + lq * 8];
    }
#pragma unroll
    for (int i = 0; i < 4; i++)
#pragma unroll
      for (int j = 0; j < 4; j++) acc[i][j] = MFMA(af[i], bfr[j], acc[i][j]);
  }
#pragma unroll
  for (int i = 0; i < 4; i++)
#pragma unroll
    for (int r = 0; r < 4; r++) {
      int slot = m0 + wm + i * 16 + lq * 4 + r;
      if (slot < count) {
        int tok = tl[slot];
        float gte = glist[e * 4096 + slot];
#pragma unroll
        for (int j = 0; j < 4; j++) {
          int col = n0 + wn + j * 16 + lr;
          atomicAdd(&outp[(size_t)tok * 1024 + col], gte * acc[i][j][r]);
        }
      }
    }
}

// ---------------------------------------------------------------------------
extern "C" void kernel_launch(void* const* d_in, const int* in_sizes, int n_in,
                              void* d_out, int out_size, void* d_ws, size_t ws_size,
                              hipStream_t stream) {
  (void)in_sizes; (void)n_in; (void)out_size; (void)ws_size;
  const float* x    = (const float*)d_in[0];
  const float* wq   = (const float*)d_in[1];
  const float* wk   = (const float*)d_in[2];
  const float* wv   = (const float*)d_in[3];
  const float* wo   = (const float*)d_in[4];
  const float* ln1g = (const float*)d_in[5];
  const float* ln1b = (const float*)d_in[6];
  const float* ln2g = (const float*)d_in[7];
  const float* ln2b = (const float*)d_in[8];
  const float* rw   = (const float*)d_in[9];
  const float* expw = (const float*)d_in[10];
  float* out = (float*)d_out;

  char* p = (char*)d_ws;
  auto take = [&](size_t bytes) -> char* {
    char* r = p;
    p += (bytes + 255) & ~(size_t)255;
    return r;
  };
  const size_t ND2 = 4096ull * 1024 * 2;  // bf16 [tokens][D]
  const size_t WD2 = 1024ull * 1024 * 2;  // bf16 [D][D]
  bf16* h_hi = (bf16*)take(ND2); bf16* h_lo = (bf16*)take(ND2);
  bf16* wqh = (bf16*)take(WD2); bf16* wql = (bf16*)take(WD2);
  bf16* wkh = (bf16*)take(WD2); bf16* wkl = (bf16*)take(WD2);
  bf16* wvh = (bf16*)take(WD2); bf16* wvl = (bf16*)take(WD2);
  bf16* woh = (bf16*)take(WD2); bf16* wol = (bf16*)take(WD2);
  bf16* q_hi = (bf16*)take(ND2); bf16* q_lo = (bf16*)take(ND2);
  bf16* k_hi = (bf16*)take(ND2); bf16* k_lo = (bf16*)take(ND2);
  bf16* v_hi = (bf16*)take(ND2); bf16* v_lo = (bf16*)take(ND2);
  bf16* a_hi = (bf16*)take(ND2); bf16* a_lo = (bf16*)take(ND2);
  bf16* h2h  = (bf16*)take(ND2);
  bf16* ewh  = (bf16*)take(8ull * 1024 * 1024 * 2);
  int*   tlist  = (int*)take(8ull * 4096 * 4);
  float* glist  = (float*)take(8ull * 4096 * 4);
  int*   cursor = (int*)take(64);
  // Vt aliases h_hi/h_lo (dead after gemm_qkv, which precedes vtrans)
  bf16* vt_hi = h_hi;
  bf16* vt_lo = h_lo;

  // weight conversions
  split_f32<<<1024, 256, 0, stream>>>(wq, wqh, wql, 1048576);
  split_f32<<<1024, 256, 0, stream>>>(wk, wkh, wkl, 1048576);
  split_f32<<<1024, 256, 0, stream>>>(wv, wvh, wvl, 1048576);
  split_f32<<<1024, 256, 0, stream>>>(wo, woh, wol, 1048576);
  cvt_f32<<<8192, 256, 0, stream>>>(expw, ewh, 8388608);

  // attention sublayer
  ln_split<<<4096, 256, 0, stream>>>(x, ln1g, ln1b, h_hi, h_lo);
  gemm_qkv<<<dim3(8, 32, 3), 256, 0, stream>>>(h_hi, h_lo, wqh, wql, wkh, wkl,
                                               wvh, wvl, q_hi, q_lo, k_hi, k_lo,
                                               v_hi, v_lo);
  vtrans<<<dim3(32, 32), 256, 0, stream>>>(v_hi, v_lo, vt_hi, vt_lo);
  attn_fused<<<dim3(32, 16), 256, 0, stream>>>(q_hi, q_lo, k_hi, k_lo, vt_hi,
                                               vt_lo, a_hi, a_lo);
  gemm_wo<<<dim3(8, 32), 256, 0, stream>>>(a_hi, a_lo, woh, wol, x, out);

  // MoE sublayer
  init_lists<<<128, 256, 0, stream>>>(tlist, glist, cursor);
  router_ln2<<<4096, 256, 0, stream>>>(out, ln2g, ln2b, rw, h2h, tlist, glist,
                                       cursor);
  gemm_moe<<<dim3(8, 32, 8), 256, 0, stream>>>(h2h, ewh, tlist, glist, cursor,
                                               out);
}

// Round 4
// 442.224 us; speedup vs baseline: 1.1785x; 1.1785x over previous
//
#include <hip/hip_runtime.h>
#include <hip/hip_bf16.h>
#include <cstdint>

// ============================================================================
// MoE transformer layer, MI355X gfx950.
// Precision: upstream of the router (LN1, QKV, attention, WO, LN2, logits) is
// ~fp32 via split-bf16 MFMA (3-pass); logits are exact fp32; expert GEMM is
// plain bf16.
// R4: router path rebuilt without global atomics (112us -> ~12us):
//   ln2f (LN2 -> fp32 h2f + bf16 h2h) -> route_wave (wave/token fp32 logits,
//   top-2, no atomics) -> build_lists (ballot prefix-scan compaction).
// ============================================================================

typedef __bf16 bf16;
typedef __bf16 bf16x8 __attribute__((ext_vector_type(8)));
typedef float f32x4 __attribute__((ext_vector_type(4)));

#define MFMA(a, b, c) __builtin_amdgcn_mfma_f32_16x16x32_bf16(a, b, c, 0, 0, 0)

__device__ __forceinline__ void gld16(void* lds, const void* g) {
  __builtin_amdgcn_global_load_lds(
      (const __attribute__((address_space(1))) void*)g,
      (__attribute__((address_space(3))) void*)lds, 16, 0, 0);
}

// ---------------------------------------------------------------------------
__global__ void split_f32(const float* __restrict__ s, bf16* __restrict__ hi,
                          bf16* __restrict__ lo, int n) {
  int i = (blockIdx.x * 256 + threadIdx.x) * 4;
  if (i >= n) return;
  float4 v = *(const float4*)(s + i);
  float a[4] = {v.x, v.y, v.z, v.w};
#pragma unroll
  for (int j = 0; j < 4; j++) {
    bf16 h = (bf16)a[j];
    hi[i + j] = h;
    lo[i + j] = (bf16)(a[j] - (float)h);
  }
}

__global__ void cvt_f32(const float* __restrict__ s, bf16* __restrict__ hi, int n) {
  int i = (blockIdx.x * 256 + threadIdx.x) * 4;
  if (i >= n) return;
  float4 v = *(const float4*)(s + i);
  hi[i] = (bf16)v.x; hi[i + 1] = (bf16)v.y;
  hi[i + 2] = (bf16)v.z; hi[i + 3] = (bf16)v.w;
}

// ---------------------------------------------------------------------------
__global__ void ln_split(const float* __restrict__ x, const float* __restrict__ g,
                         const float* __restrict__ b, bf16* __restrict__ hi,
                         bf16* __restrict__ lo) {
  int tok = blockIdx.x, t = threadIdx.x;
  float4 v = ((const float4*)(x + (size_t)tok * 1024))[t];
  float s = v.x + v.y + v.z + v.w;
  float ss = v.x * v.x + v.y * v.y + v.z * v.z + v.w * v.w;
#pragma unroll
  for (int o = 1; o < 64; o <<= 1) { s += __shfl_xor(s, o); ss += __shfl_xor(ss, o); }
  __shared__ float red[8];
  int w = t >> 6, lane = t & 63;
  if (lane == 0) { red[w] = s; red[4 + w] = ss; }
  __syncthreads();
  s = red[0] + red[1] + red[2] + red[3];
  ss = red[4] + red[5] + red[6] + red[7];
  float mu = s * (1.f / 1024.f);
  float rstd = rsqrtf(ss * (1.f / 1024.f) - mu * mu + 1e-5f);
  float4 gv = ((const float4*)g)[t], bv = ((const float4*)b)[t];
  float y[4] = {(v.x - mu) * rstd * gv.x + bv.x, (v.y - mu) * rstd * gv.y + bv.y,
                (v.z - mu) * rstd * gv.z + bv.z, (v.w - mu) * rstd * gv.w + bv.w};
  size_t o = (size_t)tok * 1024 + t * 4;
#pragma unroll
  for (int j = 0; j < 4; j++) {
    bf16 h = (bf16)y[j];
    hi[o + j] = h;
    lo[o + j] = (bf16)(y[j] - (float)h);
  }
}

// LN2: fp32 out (for exact logits) + bf16 out (expert GEMM A operand).
__global__ void ln2f(const float* __restrict__ x, const float* __restrict__ g,
                     const float* __restrict__ b, float* __restrict__ h2f,
                     bf16* __restrict__ h2h) {
  int tok = blockIdx.x, t = threadIdx.x;
  float4 v = ((const float4*)(x + (size_t)tok * 1024))[t];
  float s = v.x + v.y + v.z + v.w;
  float ss = v.x * v.x + v.y * v.y + v.z * v.z + v.w * v.w;
#pragma unroll
  for (int o = 1; o < 64; o <<= 1) { s += __shfl_xor(s, o); ss += __shfl_xor(ss, o); }
  __shared__ float red[8];
  int w = t >> 6, lane = t & 63;
  if (lane == 0) { red[w] = s; red[4 + w] = ss; }
  __syncthreads();
  s = red[0] + red[1] + red[2] + red[3];
  ss = red[4] + red[5] + red[6] + red[7];
  float mu = s * (1.f / 1024.f);
  float rstd = rsqrtf(ss * (1.f / 1024.f) - mu * mu + 1e-5f);
  float4 gv = ((const float4*)g)[t], bv = ((const float4*)b)[t];
  float4 y;
  y.x = (v.x - mu) * rstd * gv.x + bv.x;
  y.y = (v.y - mu) * rstd * gv.y + bv.y;
  y.z = (v.z - mu) * rstd * gv.z + bv.z;
  y.w = (v.w - mu) * rstd * gv.w + bv.w;
  ((float4*)(h2f + (size_t)tok * 1024))[t] = y;
  size_t o = (size_t)tok * 1024 + t * 4;
  h2h[o] = (bf16)y.x; h2h[o + 1] = (bf16)y.y;
  h2h[o + 2] = (bf16)y.z; h2h[o + 3] = (bf16)y.w;
}

// ---------------------------------------------------------------------------
// Router: one wave per token. Exact fp32 logits (coalesced float4 loads, rw
// stays L2-hot), full-wave shuffle reduce, lane 0 top-2 + gates. No atomics.
// ---------------------------------------------------------------------------
__global__ void route_wave(const float* __restrict__ h2f,
                           const float* __restrict__ rw, int* __restrict__ eid,
                           float2* __restrict__ gout) {
  int wid = (blockIdx.x * 256 + threadIdx.x) >> 6;  // token
  int lane = threadIdx.x & 63;
  const float4* xr = (const float4*)(h2f + (size_t)wid * 1024);
  float acc[8] = {0.f, 0.f, 0.f, 0.f, 0.f, 0.f, 0.f, 0.f};
#pragma unroll
  for (int it = 0; it < 4; it++) {
    float4 xv = xr[lane + 64 * it];
#pragma unroll
    for (int e = 0; e < 8; e++) {
      float4 wv = ((const float4*)(rw + e * 1024))[lane + 64 * it];
      acc[e] += xv.x * wv.x + xv.y * wv.y + xv.z * wv.z + xv.w * wv.w;
    }
  }
#pragma unroll
  for (int e = 0; e < 8; e++)
#pragma unroll
    for (int o = 1; o < 64; o <<= 1) acc[e] += __shfl_xor(acc[e], o);
  if (lane == 0) {
    int i0 = 0; float l0 = acc[0];
#pragma unroll
    for (int e = 1; e < 8; e++) if (acc[e] > l0) { l0 = acc[e]; i0 = e; }
    int i1 = -1; float l1 = -3e38f;
#pragma unroll
    for (int e = 0; e < 8; e++) if (e != i0 && acc[e] > l1) { l1 = acc[e]; i1 = e; }
    float e1 = __expf(l1 - l0);
    float den = 1.f + e1;
    eid[wid] = i0 | (i1 << 4);
    gout[wid] = make_float2(1.f / den, e1 / den);
  }
}

// ---------------------------------------------------------------------------
// Per-expert compaction: 8 blocks, ballot + popcount prefix scan, in token
// order. Writes tlist/glist/cnt and zero-pads to the next 128 boundary.
// ---------------------------------------------------------------------------
__global__ void build_lists(const int* __restrict__ eid,
                            const float2* __restrict__ gv,
                            int* __restrict__ tlist, float* __restrict__ glist,
                            int* __restrict__ cnt) {
  int e = blockIdx.x, t = threadIdx.x;
  int lane = t & 63, w = t >> 6;
  __shared__ int wt[4];
  int base = 0;
  for (int c = 0; c < 16; c++) {
    int tok = c * 256 + t;
    int pair = eid[tok];
    int e0 = pair & 15, e1 = pair >> 4;
    bool p = (e0 == e) || (e1 == e);
    float2 g2 = gv[tok];
    float gate = (e0 == e) ? g2.x : g2.y;
    unsigned long long m = __ballot(p);
    int rank = __popcll(m & ((1ull << lane) - 1ull));
    if (lane == 0) wt[w] = __popcll(m);
    __syncthreads();
    int off = base;
    for (int i = 0; i < w; i++) off += wt[i];
    if (p) {
      tlist[e * 4096 + off + rank] = tok;
      glist[e * 4096 + off + rank] = gate;
    }
    base += wt[0] + wt[1] + wt[2] + wt[3];
    __syncthreads();
  }
  if (t == 0) cnt[e] = base;
  int pad = (base + 127) & ~127;
  if (pad > 4096) pad = 4096;
  for (int i = base + t; i < pad; i += 256) {
    tlist[e * 4096 + i] = 0;
    glist[e * 4096 + i] = 0.f;
  }
}

// ---------------------------------------------------------------------------
// Split-bf16 NT GEMM core: C(128x128 fp32) = (Ah+Al) @ (Bh+Bl)^T, K=1024.
// ---------------------------------------------------------------------------
__device__ __forceinline__ void gemm_core_split(
    const bf16* __restrict__ Ah, const bf16* __restrict__ Al,
    const bf16* __restrict__ Bh, const bf16* __restrict__ Bl, int m0, int n0,
    f32x4 (&acc)[4][4]) {
  __shared__ __align__(16) bf16 As_h[4096], As_l[4096], Bs_h[4096], Bs_l[4096];
  int t = threadIdx.x, lane = t & 63, w = t >> 6;
  int i0 = t, i1 = t + 256;
  const bf16* a0h = Ah + (size_t)(m0 + (i0 >> 2)) * 1024 + (i0 & 3) * 8;
  const bf16* a1h = Ah + (size_t)(m0 + (i1 >> 2)) * 1024 + (i1 & 3) * 8;
  const bf16* a0l = Al + (size_t)(m0 + (i0 >> 2)) * 1024 + (i0 & 3) * 8;
  const bf16* a1l = Al + (size_t)(m0 + (i1 >> 2)) * 1024 + (i1 & 3) * 8;
  const bf16* b0h = Bh + (size_t)(n0 + (i0 >> 2)) * 1024 + (i0 & 3) * 8;
  const bf16* b1h = Bh + (size_t)(n0 + (i1 >> 2)) * 1024 + (i1 & 3) * 8;
  const bf16* b0l = Bl + (size_t)(n0 + (i0 >> 2)) * 1024 + (i0 & 3) * 8;
  const bf16* b1l = Bl + (size_t)(n0 + (i1 >> 2)) * 1024 + (i1 & 3) * 8;
  int wm = (w >> 1) * 64, wn = (w & 1) * 64;
  int lr = lane & 15, lq = lane >> 4;
  for (int k0 = 0; k0 < 1024; k0 += 32) {
    __syncthreads();
    gld16(&As_h[i0 * 8], a0h + k0); gld16(&As_h[i1 * 8], a1h + k0);
    gld16(&As_l[i0 * 8], a0l + k0); gld16(&As_l[i1 * 8], a1l + k0);
    gld16(&Bs_h[i0 * 8], b0h + k0); gld16(&Bs_h[i1 * 8], b1h + k0);
    gld16(&Bs_l[i0 * 8], b0l + k0); gld16(&Bs_l[i1 * 8], b1l + k0);
    __syncthreads();
    bf16x8 ah[4], al4[4], bh[4], bl4[4];
#pragma unroll
    for (int i = 0; i < 4; i++) {
      ah[i]  = *(const bf16x8*)&As_h[(wm + i * 16 + lr) * 32 + lq * 8];
      al4[i] = *(const bf16x8*)&As_l[(wm + i * 16 + lr) * 32 + lq * 8];
      bh[i]  = *(const bf16x8*)&Bs_h[(wn + i * 16 + lr) * 32 + lq * 8];
      bl4[i] = *(const bf16x8*)&Bs_l[(wn + i * 16 + lr) * 32 + lq * 8];
    }
#pragma unroll
    for (int i = 0; i < 4; i++)
#pragma unroll
      for (int j = 0; j < 4; j++) {
        f32x4 c = acc[i][j];
        c = MFMA(ah[i], bh[j], c);
        c = MFMA(ah[i], bl4[j], c);
        c = MFMA(al4[i], bh[j], c);
        acc[i][j] = c;
      }
  }
}

// QKV projection. z==0 output (Q) is pre-scaled by 1/sqrt(hd)*log2(e) so the
// attention kernel's scores are already in the exp2 domain.
__global__ __launch_bounds__(256, 2) void gemm_qkv(
    const bf16* __restrict__ hh, const bf16* __restrict__ hl,
    const bf16* __restrict__ wqh, const bf16* __restrict__ wql,
    const bf16* __restrict__ wkh, const bf16* __restrict__ wkl,
    const bf16* __restrict__ wvh, const bf16* __restrict__ wvl,
    bf16* __restrict__ qh, bf16* __restrict__ ql, bf16* __restrict__ kh,
    bf16* __restrict__ kl, bf16* __restrict__ vh, bf16* __restrict__ vl) {
  int n0 = blockIdx.x * 128, m0 = blockIdx.y * 128, z = blockIdx.z;
  const bf16 *Bh = wqh, *Bl = wql;
  bf16 *Oh = qh, *Ol = ql;
  if (z == 1) { Bh = wkh; Bl = wkl; Oh = kh; Ol = kl; }
  if (z == 2) { Bh = wvh; Bl = wvl; Oh = vh; Ol = vl; }
  float scale = (z == 0) ? (0.125f * 1.44269504f) : 1.0f;
  f32x4 acc[4][4];
#pragma unroll
  for (int i = 0; i < 4; i++)
#pragma unroll
    for (int j = 0; j < 4; j++) acc[i][j] = (f32x4){0.f, 0.f, 0.f, 0.f};
  gemm_core_split(hh, hl, Bh, Bl, m0, n0, acc);
  int t = threadIdx.x, lane = t & 63, w = t >> 6;
  int wm = (w >> 1) * 64, wn = (w & 1) * 64, lr = lane & 15, lq = lane >> 4;
#pragma unroll
  for (int i = 0; i < 4; i++)
#pragma unroll
    for (int j = 0; j < 4; j++)
#pragma unroll
      for (int r = 0; r < 4; r++) {
        size_t row = m0 + wm + i * 16 + lq * 4 + r;
        int col = n0 + wn + j * 16 + lr;
        float v = acc[i][j][r] * scale;
        bf16 h = (bf16)v;
        Oh[row * 1024 + col] = h;
        Ol[row * 1024 + col] = (bf16)(v - (float)h);
      }
}

// WO projection + residual: out_f32 = x + attn @ wo^T
__global__ __launch_bounds__(256, 2) void gemm_wo(
    const bf16* __restrict__ ah, const bf16* __restrict__ al,
    const bf16* __restrict__ bh, const bf16* __restrict__ bl,
    const float* __restrict__ resid, float* __restrict__ outp) {
  int n0 = blockIdx.x * 128, m0 = blockIdx.y * 128;
  f32x4 acc[4][4];
#pragma unroll
  for (int i = 0; i < 4; i++)
#pragma unroll
    for (int j = 0; j < 4; j++) acc[i][j] = (f32x4){0.f, 0.f, 0.f, 0.f};
  gemm_core_split(ah, al, bh, bl, m0, n0, acc);
  int t = threadIdx.x, lane = t & 63, w = t >> 6;
  int wm = (w >> 1) * 64, wn = (w & 1) * 64, lr = lane & 15, lq = lane >> 4;
#pragma unroll
  for (int i = 0; i < 4; i++)
#pragma unroll
    for (int j = 0; j < 4; j++)
#pragma unroll
      for (int r = 0; r < 4; r++) {
        size_t row = m0 + wm + i * 16 + lq * 4 + r;
        int col = n0 + wn + j * 16 + lr;
        outp[row * 1024 + col] = resid[row * 1024 + col] + acc[i][j][r];
      }
}

// ---------------------------------------------------------------------------
// V transpose: V[b*2048+s][head*64+d] -> Vt[(b*16+head)*64+d][s] (per buffer).
// ---------------------------------------------------------------------------
__global__ void vtrans(const bf16* __restrict__ vh, const bf16* __restrict__ vl,
                       bf16* __restrict__ vth, bf16* __restrict__ vtl) {
  int bh = blockIdx.y, s0 = blockIdx.x * 64;
  int b = bh >> 4, h = bh & 15;
  int t = threadIdx.x;
  __shared__ __align__(16) bf16 tile[4096];
  int r = t >> 2, c4 = t & 3;
  int dr = t >> 2, tg = t & 3;
#pragma unroll
  for (int pass = 0; pass < 2; pass++) {
    const bf16* src = pass ? vl : vh;
    bf16* dst = pass ? vtl : vth;
    if (pass) __syncthreads();
    const bf16* sp = src + (size_t)(b * 2048 + s0 + r) * 1024 + h * 64 + c4 * 16;
    bf16x8 v0 = *(const bf16x8*)sp;
    bf16x8 v1 = *(const bf16x8*)(sp + 8);
#pragma unroll
    for (int j = 0; j < 8; j++) {
      int d0 = c4 * 16 + j, d1 = c4 * 16 + 8 + j;
      tile[d0 * 64 + (r ^ ((d0 >> 3) << 3))] = v0[j];
      tile[d1 * 64 + (r ^ ((d1 >> 3) << 3))] = v1[j];
    }
    __syncthreads();
#pragma unroll
    for (int hf = 0; hf < 2; hf++) {
      int tok = tg * 16 + hf * 8;
      bf16x8 o = *(const bf16x8*)&tile[dr * 64 + (tok ^ ((dr >> 3) << 3))];
      *(bf16x8*)(dst + (size_t)(bh * 64 + dr) * 2048 + s0 + tok) = o;
    }
  }
}

// ---------------------------------------------------------------------------
// Flash attention, split-bf16, no running max (scores bounded; Q pre-scaled
// into exp2 domain). Block = 128 queries x 1 head, 4 waves x 32 queries.
// ---------------------------------------------------------------------------
__global__ __launch_bounds__(256, 2) void attn_fused(
    const bf16* __restrict__ qh, const bf16* __restrict__ ql,
    const bf16* __restrict__ kh, const bf16* __restrict__ kl,
    const bf16* __restrict__ vth, const bf16* __restrict__ vtl,
    bf16* __restrict__ oh, bf16* __restrict__ ol) {
  const int S = 2048, D = 1024;
  int qt = 15 - blockIdx.y;
  int hb = blockIdx.x;
  int head = hb & 15, b = hb >> 4;
  int qb = qt * 128;
  int t = threadIdx.x, lane = t & 63, w = t >> 6;
  int lr = lane & 15, lq = lane >> 4;
  int base = b * S, hcol = head * 64;

  __shared__ __align__(16) bf16 Kh_s[4096], Kl_s[4096];
  __shared__ __align__(16) bf16 Vh_s[4096], Vl_s[4096];
  __shared__ __align__(16) bf16 Ph_s[4][1024], Pl_s[4][1024];

  bf16x8 qfh[2][2], qfl[2][2];
#pragma unroll
  for (int qr = 0; qr < 2; qr++) {
    const bf16* p1 = qh + (size_t)(base + qb + w * 32 + qr * 16 + lr) * D + hcol + lq * 8;
    const bf16* p2 = ql + (size_t)(base + qb + w * 32 + qr * 16 + lr) * D + hcol + lq * 8;
    qfh[qr][0] = *(const bf16x8*)p1; qfh[qr][1] = *(const bf16x8*)(p1 + 32);
    qfl[qr][0] = *(const bf16x8*)p2; qfl[qr][1] = *(const bf16x8*)(p2 + 32);
  }
  f32x4 O[2][4];
  float lrow[2][4];
#pragma unroll
  for (int qr = 0; qr < 2; qr++)
#pragma unroll
    for (int j = 0; j < 4; j++) {
      O[qr][j] = (f32x4){0.f, 0.f, 0.f, 0.f};
      lrow[qr][j] = 0.f;
    }

  int r0 = t >> 3, p0 = t & 7;
  int r1 = (t + 256) >> 3, p1 = (t + 256) & 7;
  int g0 = p0 ^ (r0 & 7), g1 = p1 ^ (r1 & 7);
  const bf16* k0hp = kh + (size_t)(base + r0) * D + hcol + g0 * 8;
  const bf16* k1hp = kh + (size_t)(base + r1) * D + hcol + g1 * 8;
  const bf16* k0lp = kl + (size_t)(base + r0) * D + hcol + g0 * 8;
  const bf16* k1lp = kl + (size_t)(base + r1) * D + hcol + g1 * 8;
  const bf16* v0hp = vth + (size_t)(hb * 64 + r0) * 2048 + g0 * 8;
  const bf16* v1hp = vth + (size_t)(hb * 64 + r1) * 2048 + g1 * 8;
  const bf16* v0lp = vtl + (size_t)(hb * 64 + r0) * 2048 + g0 * 8;
  const bf16* v1lp = vtl + (size_t)(hb * 64 + r1) * 2048 + g1 * 8;

  int qwmin = qb + w * 32;
  int pswz = ((lr >> 2) & 1) << 4;

  for (int kt = 0; kt <= qb + 64; kt += 64) {
    __syncthreads();
    gld16(&Kh_s[t * 8], k0hp + (size_t)kt * D);
    gld16(&Kh_s[2048 + t * 8], k1hp + (size_t)kt * D);
    gld16(&Kl_s[t * 8], k0lp + (size_t)kt * D);
    gld16(&Kl_s[2048 + t * 8], k1lp + (size_t)kt * D);
    gld16(&Vh_s[t * 8], v0hp + kt);
    gld16(&Vh_s[2048 + t * 8], v1hp + kt);
    gld16(&Vl_s[t * 8], v0lp + kt);
    gld16(&Vl_s[2048 + t * 8], v1lp + kt);
    __syncthreads();
    if (kt > qwmin + 31) continue;
    bool need_mask = (kt + 63 > qwmin);
#pragma unroll
    for (int hf = 0; hf < 2; hf++) {
      f32x4 sc[2][2];
#pragma unroll
      for (int tt = 0; tt < 2; tt++) {
        int key16 = (hf * 2 + tt) * 16 + lr;
        int gl = (lq ^ (key16 & 7)) * 8;
        int gh = ((4 + lq) ^ (key16 & 7)) * 8;
        bf16x8 k0 = *(const bf16x8*)&Kh_s[key16 * 64 + gl];
        bf16x8 k1 = *(const bf16x8*)&Kh_s[key16 * 64 + gh];
        bf16x8 m0 = *(const bf16x8*)&Kl_s[key16 * 64 + gl];
        bf16x8 m1 = *(const bf16x8*)&Kl_s[key16 * 64 + gh];
#pragma unroll
        for (int qr = 0; qr < 2; qr++) {
          f32x4 s = (f32x4){0.f, 0.f, 0.f, 0.f};
          s = MFMA(qfh[qr][0], k0, s); s = MFMA(qfh[qr][1], k1, s);
          s = MFMA(qfh[qr][0], m0, s); s = MFMA(qfh[qr][1], m1, s);
          s = MFMA(qfl[qr][0], k0, s); s = MFMA(qfl[qr][1], k1, s);
          sc[qr][tt] = s;
        }
      }
#pragma unroll
      for (int qr = 0; qr < 2; qr++)
#pragma unroll
        for (int tt = 0; tt < 2; tt++) {
          int key = kt + (hf * 2 + tt) * 16 + lr;
#pragma unroll
          for (int r = 0; r < 4; r++) {
            float s = sc[qr][tt][r];
            if (need_mask) {
              int q = qwmin + qr * 16 + lq * 4 + r;
              s = (key <= q) ? s : -30000.f;
            }
            float pv = __builtin_amdgcn_exp2f(s);
            lrow[qr][r] += pv;
            bf16 ph = (bf16)pv;
            int col = (tt * 16 + lr) ^ ((lq & 1) << 4);
            int idx = (qr * 16 + lq * 4 + r) * 32 + col;
            Ph_s[w][idx] = ph;
            Pl_s[w][idx] = (bf16)(pv - (float)ph);
          }
        }
      bf16x8 vbh[4], vbl[4];
#pragma unroll
      for (int j = 0; j < 4; j++) {
        int d = j * 16 + lr;
        int gv = ((hf * 4 + lq) ^ (d & 7)) * 8;
        vbh[j] = *(const bf16x8*)&Vh_s[d * 64 + gv];
        vbl[j] = *(const bf16x8*)&Vl_s[d * 64 + gv];
      }
#pragma unroll
      for (int qr = 0; qr < 2; qr++) {
        int poff = (qr * 16 + lr) * 32 + ((lq * 8) ^ pswz);
        bf16x8 pf = *(const bf16x8*)&Ph_s[w][poff];
        bf16x8 pl2 = *(const bf16x8*)&Pl_s[w][poff];
#pragma unroll
        for (int j = 0; j < 4; j++) {
          f32x4 c = O[qr][j];
          c = MFMA(pf, vbh[j], c);
          c = MFMA(pf, vbl[j], c);
          c = MFMA(pl2, vbh[j], c);
          O[qr][j] = c;
        }
      }
    }
  }
#pragma unroll
  for (int qr = 0; qr < 2; qr++) {
    float linv[4];
#pragma unroll
    for (int r = 0; r < 4; r++) {
      float l = lrow[qr][r];
      l += __shfl_xor(l, 1); l += __shfl_xor(l, 2);
      l += __shfl_xor(l, 4); l += __shfl_xor(l, 8);
      linv[r] = 1.f / l;
    }
#pragma unroll
    for (int j = 0; j < 4; j++)
#pragma unroll
      for (int r = 0; r < 4; r++) {
        size_t tok = (size_t)(base + qb + w * 32 + qr * 16 + lq * 4 + r);
        int col = hcol + j * 16 + lr;
        float v = O[qr][j][r] * linv[r];
        bf16 h = (bf16)v;
        oh[tok * D + col] = h;
        ol[tok * D + col] = (bf16)(v - (float)h);
      }
  }
}

// ---------------------------------------------------------------------------
// Routed expert GEMM (plain bf16): gather via tlist, atomicAdd scatter.
// ---------------------------------------------------------------------------
__global__ __launch_bounds__(256, 2) void gemm_moe(
    const bf16* __restrict__ A, const bf16* __restrict__ W,
    const int* __restrict__ tlist, const float* __restrict__ glist,
    const int* __restrict__ cnt, float* __restrict__ outp) {
  int e = blockIdx.z;
  int count = cnt[e];
  int m0 = blockIdx.y * 128;
  if (m0 >= count) return;
  int n0 = blockIdx.x * 128;
  const int* tl = tlist + e * 4096;
  const bf16* B = W + (size_t)e * 1024 * 1024;
  __shared__ __align__(16) bf16 As[4096], Bs[4096];
  int t = threadIdx.x, lane = t & 63, w = t >> 6;
  int i0 = t, i1 = t + 256;
  int ra = tl[m0 + (i0 >> 2)], rb = tl[m0 + (i1 >> 2)];
  const bf16* a0 = A + (size_t)ra * 1024 + (i0 & 3) * 8;
  const bf16* a1 = A + (size_t)rb * 1024 + (i1 & 3) * 8;
  const bf16* b0 = B + (size_t)(n0 + (i0 >> 2)) * 1024 + (i0 & 3) * 8;
  const bf16* b1 = B + (size_t)(n0 + (i1 >> 2)) * 1024 + (i1 & 3) * 8;
  int wm = (w >> 1) * 64, wn = (w & 1) * 64, lr = lane & 15, lq = lane >> 4;
  f32x4 acc[4][4];
#pragma unroll
  for (int i = 0; i < 4; i++)
#pragma unroll
    for (int j = 0; j < 4; j++) acc[i][j] = (f32x4){0.f, 0.f, 0.f, 0.f};
  for (int k0 = 0; k0 < 1024; k0 += 32) {
    __syncthreads();
    gld16(&As[i0 * 8], a0 + k0); gld16(&As[i1 * 8], a1 + k0);
    gld16(&Bs[i0 * 8], b0 + k0); gld16(&Bs[i1 * 8], b1 + k0);
    __syncthreads();
    bf16x8 af[4], bfr[4];
#pragma unroll
    for (int i = 0; i < 4; i++) {
      af[i] = *(const bf16x8*)&As[(wm + i * 16 + lr) * 32 + lq * 8];
      bfr[i] = *(const bf16x8*)&Bs[(wn + i * 16 + lr) * 32 + lq * 8];
    }
#pragma unroll
    for (int i = 0; i < 4; i++)
#pragma unroll
      for (int j = 0; j < 4; j++) acc[i][j] = MFMA(af[i], bfr[j], acc[i][j]);
  }
#pragma unroll
  for (int i = 0; i < 4; i++)
#pragma unroll
    for (int r = 0; r < 4; r++) {
      int slot = m0 + wm + i * 16 + lq * 4 + r;
      if (slot < count) {
        int tok = tl[slot];
        float gte = glist[e * 4096 + slot];
#pragma unroll
        for (int j = 0; j < 4; j++) {
          int col = n0 + wn + j * 16 + lr;
          atomicAdd(&outp[(size_t)tok * 1024 + col], gte * acc[i][j][r]);
        }
      }
    }
}

// ---------------------------------------------------------------------------
extern "C" void kernel_launch(void* const* d_in, const int* in_sizes, int n_in,
                              void* d_out, int out_size, void* d_ws, size_t ws_size,
                              hipStream_t stream) {
  (void)in_sizes; (void)n_in; (void)out_size; (void)ws_size;
  const float* x    = (const float*)d_in[0];
  const float* wq   = (const float*)d_in[1];
  const float* wk   = (const float*)d_in[2];
  const float* wv   = (const float*)d_in[3];
  const float* wo   = (const float*)d_in[4];
  const float* ln1g = (const float*)d_in[5];
  const float* ln1b = (const float*)d_in[6];
  const float* ln2g = (const float*)d_in[7];
  const float* ln2b = (const float*)d_in[8];
  const float* rw   = (const float*)d_in[9];
  const float* expw = (const float*)d_in[10];
  float* out = (float*)d_out;

  char* p = (char*)d_ws;
  auto take = [&](size_t bytes) -> char* {
    char* r = p;
    p += (bytes + 255) & ~(size_t)255;
    return r;
  };
  const size_t ND2 = 4096ull * 1024 * 2;  // bf16 [tokens][D]
  const size_t WD2 = 1024ull * 1024 * 2;  // bf16 [D][D]
  bf16* h_hi = (bf16*)take(ND2); bf16* h_lo = (bf16*)take(ND2);
  bf16* wqh = (bf16*)take(WD2); bf16* wql = (bf16*)take(WD2);
  bf16* wkh = (bf16*)take(WD2); bf16* wkl = (bf16*)take(WD2);
  bf16* wvh = (bf16*)take(WD2); bf16* wvl = (bf16*)take(WD2);
  bf16* woh = (bf16*)take(WD2); bf16* wol = (bf16*)take(WD2);
  bf16* q_hi = (bf16*)take(ND2); bf16* q_lo = (bf16*)take(ND2);
  bf16* k_hi = (bf16*)take(ND2); bf16* k_lo = (bf16*)take(ND2);
  bf16* v_hi = (bf16*)take(ND2); bf16* v_lo = (bf16*)take(ND2);
  bf16* a_hi = (bf16*)take(ND2); bf16* a_lo = (bf16*)take(ND2);
  bf16* h2h  = (bf16*)take(ND2);
  bf16* ewh  = (bf16*)take(8ull * 1024 * 1024 * 2);
  int*   tlist  = (int*)take(8ull * 4096 * 4);
  float* glist  = (float*)take(8ull * 4096 * 4);
  int*   cnt    = (int*)take(64);
  int*   reid   = (int*)take(4096 * 4);
  float2* rg    = (float2*)take(4096 * 8);
  // Vt aliases h_hi/h_lo (dead after gemm_qkv; used only by attn).
  bf16* vt_hi = h_hi;
  bf16* vt_lo = h_lo;
  // h2f (fp32, 16.8MB) aliases h_hi+h_lo (contiguous, dead after attn).
  float* h2f = (float*)h_hi;

  // weight conversions
  split_f32<<<1024, 256, 0, stream>>>(wq, wqh, wql, 1048576);
  split_f32<<<1024, 256, 0, stream>>>(wk, wkh, wkl, 1048576);
  split_f32<<<1024, 256, 0, stream>>>(wv, wvh, wvl, 1048576);
  split_f32<<<1024, 256, 0, stream>>>(wo, woh, wol, 1048576);
  cvt_f32<<<8192, 256, 0, stream>>>(expw, ewh, 8388608);

  // attention sublayer
  ln_split<<<4096, 256, 0, stream>>>(x, ln1g, ln1b, h_hi, h_lo);
  gemm_qkv<<<dim3(8, 32, 3), 256, 0, stream>>>(h_hi, h_lo, wqh, wql, wkh, wkl,
                                               wvh, wvl, q_hi, q_lo, k_hi, k_lo,
                                               v_hi, v_lo);
  vtrans<<<dim3(32, 32), 256, 0, stream>>>(v_hi, v_lo, vt_hi, vt_lo);
  attn_fused<<<dim3(32, 16), 256, 0, stream>>>(q_hi, q_lo, k_hi, k_lo, vt_hi,
                                               vt_lo, a_hi, a_lo);
  gemm_wo<<<dim3(8, 32), 256, 0, stream>>>(a_hi, a_lo, woh, wol, x, out);

  // MoE sublayer (atomic-free routing)
  ln2f<<<4096, 256, 0, stream>>>(out, ln2g, ln2b, h2f, h2h);
  route_wave<<<1024, 256, 0, stream>>>(h2f, rw, reid, rg);
  build_lists<<<8, 256, 0, stream>>>(reid, rg, tlist, glist, cnt);
  gemm_moe<<<dim3(8, 32, 8), 256, 0, stream>>>(h2h, ewh, tlist, glist, cnt,
                                               out);
}

// Round 5
// 414.629 us; speedup vs baseline: 1.2569x; 1.0666x over previous
//
#include <hip/hip_runtime.h>
#include <hip/hip_bf16.h>
#include <cstdint>

// ============================================================================
// MoE transformer layer, MI355X gfx950.
// Precision: upstream of the router (LN1, QKV, attention, WO, LN2, logits) is
// ~fp32 via split-bf16 MFMA (3-pass); logits exact fp32; expert GEMM plain
// bf16; routed MoE via ballot-compacted per-expert lists (no atomics in
// routing; atomicAdd scatter in expert GEMM).
// R5: attention on 32x32x16 MFMA with packed-P (hi|lo in one u32, stride-68
// LDS rows, conflict-free by construction); V transposed in gemm_qkv epilogue
// (vtrans kernel deleted); weight prep fused to 1 kernel; LN2+router fused.
// ============================================================================

typedef __bf16 bf16;
typedef __bf16 bf16x8 __attribute__((ext_vector_type(8)));
typedef __bf16 bf16x4 __attribute__((ext_vector_type(4)));
typedef float f32x4 __attribute__((ext_vector_type(4)));
typedef float f32x16 __attribute__((ext_vector_type(16)));

#define MFMA(a, b, c) __builtin_amdgcn_mfma_f32_16x16x32_bf16(a, b, c, 0, 0, 0)
#define MFMA32(a, b, c) __builtin_amdgcn_mfma_f32_32x32x16_bf16(a, b, c, 0, 0, 0)

__device__ __forceinline__ void gld16(void* lds, const void* g) {
  __builtin_amdgcn_global_load_lds(
      (const __attribute__((address_space(1))) void*)g,
      (__attribute__((address_space(3))) void*)lds, 16, 0, 0);
}

__device__ __forceinline__ uint32_t pack_hilo(float pv) {
  bf16 h = (bf16)pv;
  bf16 l = (bf16)(pv - (float)h);
  union { bf16 b[2]; uint32_t u; } cv;
  cv.b[0] = h; cv.b[1] = l;
  return cv.u;
}

// ---------------------------------------------------------------------------
// Fused weight prep: split wq/wk/wv/wo into (hi,lo) bf16; cvt expw to bf16.
// blocks 0..4095: splits (1024 per weight); 4096..12287: expert cvt.
// ---------------------------------------------------------------------------
__global__ void prep_weights(const float* __restrict__ wq, const float* __restrict__ wk,
                             const float* __restrict__ wv, const float* __restrict__ wo,
                             const float* __restrict__ expw,
                             bf16* __restrict__ wqh, bf16* __restrict__ wql,
                             bf16* __restrict__ wkh, bf16* __restrict__ wkl,
                             bf16* __restrict__ wvh, bf16* __restrict__ wvl,
                             bf16* __restrict__ woh, bf16* __restrict__ wol,
                             bf16* __restrict__ ewh) {
  int bid = blockIdx.x;
  if (bid < 4096) {
    int wsel = bid >> 10;
    const float* src = wsel == 0 ? wq : wsel == 1 ? wk : wsel == 2 ? wv : wo;
    bf16* hi = wsel == 0 ? wqh : wsel == 1 ? wkh : wsel == 2 ? wvh : woh;
    bf16* lo = wsel == 0 ? wql : wsel == 1 ? wkl : wsel == 2 ? wvl : wol;
    int i = ((bid & 1023) * 256 + threadIdx.x) * 4;
    float4 v = *(const float4*)(src + i);
    float a[4] = {v.x, v.y, v.z, v.w};
#pragma unroll
    for (int j = 0; j < 4; j++) {
      bf16 h = (bf16)a[j];
      hi[i + j] = h;
      lo[i + j] = (bf16)(a[j] - (float)h);
    }
  } else {
    int i = ((bid - 4096) * 256 + threadIdx.x) * 4;
    float4 v = *(const float4*)(expw + i);
    ewh[i] = (bf16)v.x; ewh[i + 1] = (bf16)v.y;
    ewh[i + 2] = (bf16)v.z; ewh[i + 3] = (bf16)v.w;
  }
}

// ---------------------------------------------------------------------------
__global__ void ln_split(const float* __restrict__ x, const float* __restrict__ g,
                         const float* __restrict__ b, bf16* __restrict__ hi,
                         bf16* __restrict__ lo) {
  int tok = blockIdx.x, t = threadIdx.x;
  float4 v = ((const float4*)(x + (size_t)tok * 1024))[t];
  float s = v.x + v.y + v.z + v.w;
  float ss = v.x * v.x + v.y * v.y + v.z * v.z + v.w * v.w;
#pragma unroll
  for (int o = 1; o < 64; o <<= 1) { s += __shfl_xor(s, o); ss += __shfl_xor(ss, o); }
  __shared__ float red[8];
  int w = t >> 6, lane = t & 63;
  if (lane == 0) { red[w] = s; red[4 + w] = ss; }
  __syncthreads();
  s = red[0] + red[1] + red[2] + red[3];
  ss = red[4] + red[5] + red[6] + red[7];
  float mu = s * (1.f / 1024.f);
  float rstd = rsqrtf(ss * (1.f / 1024.f) - mu * mu + 1e-5f);
  float4 gv = ((const float4*)g)[t], bv = ((const float4*)b)[t];
  float y[4] = {(v.x - mu) * rstd * gv.x + bv.x, (v.y - mu) * rstd * gv.y + bv.y,
                (v.z - mu) * rstd * gv.z + bv.z, (v.w - mu) * rstd * gv.w + bv.w};
  size_t o = (size_t)tok * 1024 + t * 4;
#pragma unroll
  for (int j = 0; j < 4; j++) {
    bf16 h = (bf16)y[j];
    hi[o + j] = h;
    lo[o + j] = (bf16)(y[j] - (float)h);
  }
}

// ---------------------------------------------------------------------------
// Fused LN2 + router: exact fp32 logits from LDS h2, top-2, gates. No atomics.
// Also emits h2 bf16 (expert GEMM A operand).
// ---------------------------------------------------------------------------
__global__ void ln2route(const float* __restrict__ x1, const float* __restrict__ g,
                         const float* __restrict__ b, const float* __restrict__ rw,
                         bf16* __restrict__ h2h, int* __restrict__ eid,
                         float2* __restrict__ gout) {
  int tok = blockIdx.x, t = threadIdx.x;
  float4 v = ((const float4*)(x1 + (size_t)tok * 1024))[t];
  float s = v.x + v.y + v.z + v.w;
  float ss = v.x * v.x + v.y * v.y + v.z * v.z + v.w * v.w;
#pragma unroll
  for (int o = 1; o < 64; o <<= 1) { s += __shfl_xor(s, o); ss += __shfl_xor(ss, o); }
  __shared__ float red[8];
  __shared__ float h2s[1024];
  __shared__ float lg[8];
  int w = t >> 6, lane = t & 63;
  if (lane == 0) { red[w] = s; red[4 + w] = ss; }
  __syncthreads();
  s = red[0] + red[1] + red[2] + red[3];
  ss = red[4] + red[5] + red[6] + red[7];
  float mu = s * (1.f / 1024.f);
  float rstd = rsqrtf(ss * (1.f / 1024.f) - mu * mu + 1e-5f);
  float4 gv = ((const float4*)g)[t], bv = ((const float4*)b)[t];
  float4 y;
  y.x = (v.x - mu) * rstd * gv.x + bv.x;
  y.y = (v.y - mu) * rstd * gv.y + bv.y;
  y.z = (v.z - mu) * rstd * gv.z + bv.z;
  y.w = (v.w - mu) * rstd * gv.w + bv.w;
  ((float4*)h2s)[t] = y;
  size_t o = (size_t)tok * 1024 + t * 4;
  h2h[o] = (bf16)y.x; h2h[o + 1] = (bf16)y.y;
  h2h[o + 2] = (bf16)y.z; h2h[o + 3] = (bf16)y.w;
  __syncthreads();
  float a0 = 0.f, a1 = 0.f;
  const float4* r0 = (const float4*)(rw + (2 * w) * 1024);
  const float4* r1 = (const float4*)(rw + (2 * w + 1) * 1024);
#pragma unroll
  for (int it = 0; it < 4; it++) {
    float4 xv = ((const float4*)h2s)[lane + 64 * it];
    float4 w0 = r0[lane + 64 * it];
    float4 w1 = r1[lane + 64 * it];
    a0 += xv.x * w0.x + xv.y * w0.y + xv.z * w0.z + xv.w * w0.w;
    a1 += xv.x * w1.x + xv.y * w1.y + xv.z * w1.z + xv.w * w1.w;
  }
#pragma unroll
  for (int o2 = 1; o2 < 64; o2 <<= 1) {
    a0 += __shfl_xor(a0, o2);
    a1 += __shfl_xor(a1, o2);
  }
  if (lane == 0) { lg[2 * w] = a0; lg[2 * w + 1] = a1; }
  __syncthreads();
  if (t == 0) {
    int i0 = 0; float l0 = lg[0];
#pragma unroll
    for (int e = 1; e < 8; e++) if (lg[e] > l0) { l0 = lg[e]; i0 = e; }
    int i1 = -1; float l1 = -3e38f;
#pragma unroll
    for (int e = 0; e < 8; e++) if (e != i0 && lg[e] > l1) { l1 = lg[e]; i1 = e; }
    float e1 = __expf(l1 - l0);
    float den = 1.f + e1;
    eid[tok] = i0 | (i1 << 4);
    gout[tok] = make_float2(1.f / den, e1 / den);
  }
}

// ---------------------------------------------------------------------------
// Per-expert compaction: 8 blocks, ballot + popcount prefix scan, token order.
// ---------------------------------------------------------------------------
__global__ void build_lists(const int* __restrict__ eid,
                            const float2* __restrict__ gv,
                            int* __restrict__ tlist, float* __restrict__ glist,
                            int* __restrict__ cnt) {
  int e = blockIdx.x, t = threadIdx.x;
  int lane = t & 63, w = t >> 6;
  __shared__ int wt[4];
  int base = 0;
  for (int c = 0; c < 16; c++) {
    int tok = c * 256 + t;
    int pair = eid[tok];
    int e0 = pair & 15, e1 = pair >> 4;
    bool p = (e0 == e) || (e1 == e);
    float2 g2 = gv[tok];
    float gate = (e0 == e) ? g2.x : g2.y;
    unsigned long long m = __ballot(p);
    int rank = __popcll(m & ((1ull << lane) - 1ull));
    if (lane == 0) wt[w] = __popcll(m);
    __syncthreads();
    int off = base;
    for (int i = 0; i < w; i++) off += wt[i];
    if (p) {
      tlist[e * 4096 + off + rank] = tok;
      glist[e * 4096 + off + rank] = gate;
    }
    base += wt[0] + wt[1] + wt[2] + wt[3];
    __syncthreads();
  }
  if (t == 0) cnt[e] = base;
  int pad = (base + 127) & ~127;
  if (pad > 4096) pad = 4096;
  for (int i = base + t; i < pad; i += 256) {
    tlist[e * 4096 + i] = 0;
    glist[e * 4096 + i] = 0.f;
  }
}

// ---------------------------------------------------------------------------
// Split-bf16 NT GEMM core: C(128x128 fp32) = (Ah+Al) @ (Bh+Bl)^T, K=1024.
// ---------------------------------------------------------------------------
__device__ __forceinline__ void gemm_core_split(
    const bf16* __restrict__ Ah, const bf16* __restrict__ Al,
    const bf16* __restrict__ Bh, const bf16* __restrict__ Bl, int m0, int n0,
    f32x4 (&acc)[4][4]) {
  __shared__ __align__(16) bf16 As_h[4096], As_l[4096], Bs_h[4096], Bs_l[4096];
  int t = threadIdx.x, lane = t & 63, w = t >> 6;
  int i0 = t, i1 = t + 256;
  const bf16* a0h = Ah + (size_t)(m0 + (i0 >> 2)) * 1024 + (i0 & 3) * 8;
  const bf16* a1h = Ah + (size_t)(m0 + (i1 >> 2)) * 1024 + (i1 & 3) * 8;
  const bf16* a0l = Al + (size_t)(m0 + (i0 >> 2)) * 1024 + (i0 & 3) * 8;
  const bf16* a1l = Al + (size_t)(m0 + (i1 >> 2)) * 1024 + (i1 & 3) * 8;
  const bf16* b0h = Bh + (size_t)(n0 + (i0 >> 2)) * 1024 + (i0 & 3) * 8;
  const bf16* b1h = Bh + (size_t)(n0 + (i1 >> 2)) * 1024 + (i1 & 3) * 8;
  const bf16* b0l = Bl + (size_t)(n0 + (i0 >> 2)) * 1024 + (i0 & 3) * 8;
  const bf16* b1l = Bl + (size_t)(n0 + (i1 >> 2)) * 1024 + (i1 & 3) * 8;
  int wm = (w >> 1) * 64, wn = (w & 1) * 64;
  int lr = lane & 15, lq = lane >> 4;
  for (int k0 = 0; k0 < 1024; k0 += 32) {
    __syncthreads();
    gld16(&As_h[i0 * 8], a0h + k0); gld16(&As_h[i1 * 8], a1h + k0);
    gld16(&As_l[i0 * 8], a0l + k0); gld16(&As_l[i1 * 8], a1l + k0);
    gld16(&Bs_h[i0 * 8], b0h + k0); gld16(&Bs_h[i1 * 8], b1h + k0);
    gld16(&Bs_l[i0 * 8], b0l + k0); gld16(&Bs_l[i1 * 8], b1l + k0);
    __syncthreads();
    bf16x8 ah[4], al4[4], bh[4], bl4[4];
#pragma unroll
    for (int i = 0; i < 4; i++) {
      ah[i]  = *(const bf16x8*)&As_h[(wm + i * 16 + lr) * 32 + lq * 8];
      al4[i] = *(const bf16x8*)&As_l[(wm + i * 16 + lr) * 32 + lq * 8];
      bh[i]  = *(const bf16x8*)&Bs_h[(wn + i * 16 + lr) * 32 + lq * 8];
      bl4[i] = *(const bf16x8*)&Bs_l[(wn + i * 16 + lr) * 32 + lq * 8];
    }
#pragma unroll
    for (int i = 0; i < 4; i++)
#pragma unroll
      for (int j = 0; j < 4; j++) {
        f32x4 c = acc[i][j];
        c = MFMA(ah[i], bh[j], c);
        c = MFMA(ah[i], bl4[j], c);
        c = MFMA(al4[i], bh[j], c);
        acc[i][j] = c;
      }
  }
}

// QKV projection. z==0 (Q) pre-scaled into exp2 domain. z==2 (V) is written
// DIRECTLY TRANSPOSED to vt[(b*16+head)*64+d][s] (attention B-operand layout),
// packing 4 consecutive tokens per 8B store.
__global__ __launch_bounds__(256, 2) void gemm_qkv(
    const bf16* __restrict__ hh, const bf16* __restrict__ hl,
    const bf16* __restrict__ wqh, const bf16* __restrict__ wql,
    const bf16* __restrict__ wkh, const bf16* __restrict__ wkl,
    const bf16* __restrict__ wvh, const bf16* __restrict__ wvl,
    bf16* __restrict__ qh, bf16* __restrict__ ql, bf16* __restrict__ kh,
    bf16* __restrict__ kl, bf16* __restrict__ vth, bf16* __restrict__ vtl) {
  int n0 = blockIdx.x * 128, m0 = blockIdx.y * 128, z = blockIdx.z;
  const bf16 *Bh = wqh, *Bl = wql;
  if (z == 1) { Bh = wkh; Bl = wkl; }
  if (z == 2) { Bh = wvh; Bl = wvl; }
  f32x4 acc[4][4];
#pragma unroll
  for (int i = 0; i < 4; i++)
#pragma unroll
    for (int j = 0; j < 4; j++) acc[i][j] = (f32x4){0.f, 0.f, 0.f, 0.f};
  gemm_core_split(hh, hl, Bh, Bl, m0, n0, acc);
  int t = threadIdx.x, lane = t & 63, w = t >> 6;
  int wm = (w >> 1) * 64, wn = (w & 1) * 64, lr = lane & 15, lq = lane >> 4;
  if (z < 2) {
    bf16* Oh = z == 0 ? qh : kh;
    bf16* Ol = z == 0 ? ql : kl;
    float scale = (z == 0) ? (0.125f * 1.44269504f) : 1.0f;
#pragma unroll
    for (int i = 0; i < 4; i++)
#pragma unroll
      for (int j = 0; j < 4; j++)
#pragma unroll
        for (int r = 0; r < 4; r++) {
          size_t row = m0 + wm + i * 16 + lq * 4 + r;
          int col = n0 + wn + j * 16 + lr;
          float v = acc[i][j][r] * scale;
          bf16 h = (bf16)v;
          Oh[row * 1024 + col] = h;
          Ol[row * 1024 + col] = (bf16)(v - (float)h);
        }
  } else {
    int bb = m0 >> 11;           // batch index (128-row tile never crosses)
    int srow0 = m0 & 2047;
#pragma unroll
    for (int i = 0; i < 4; i++)
#pragma unroll
      for (int j = 0; j < 4; j++) {
        int col = n0 + wn + j * 16 + lr;  // dim in [0,1024)
        int head = col >> 6, d = col & 63;
        int s = srow0 + wm + i * 16 + lq * 4;
        bf16x4 hv, lv;
#pragma unroll
        for (int r = 0; r < 4; r++) {
          float v = acc[i][j][r];
          bf16 h = (bf16)v;
          hv[r] = h;
          lv[r] = (bf16)(v - (float)h);
        }
        size_t off = ((size_t)((bb * 16 + head) * 64 + d)) * 2048 + s;
        *(bf16x4*)(vth + off) = hv;
        *(bf16x4*)(vtl + off) = lv;
      }
  }
}

// WO projection + residual: out_f32 = x + attn @ wo^T
__global__ __launch_bounds__(256, 2) void gemm_wo(
    const bf16* __restrict__ ah, const bf16* __restrict__ al,
    const bf16* __restrict__ bh, const bf16* __restrict__ bl,
    const float* __restrict__ resid, float* __restrict__ outp) {
  int n0 = blockIdx.x * 128, m0 = blockIdx.y * 128;
  f32x4 acc[4][4];
#pragma unroll
  for (int i = 0; i < 4; i++)
#pragma unroll
    for (int j = 0; j < 4; j++) acc[i][j] = (f32x4){0.f, 0.f, 0.f, 0.f};
  gemm_core_split(ah, al, bh, bl, m0, n0, acc);
  int t = threadIdx.x, lane = t & 63, w = t >> 6;
  int wm = (w >> 1) * 64, wn = (w & 1) * 64, lr = lane & 15, lq = lane >> 4;
#pragma unroll
  for (int i = 0; i < 4; i++)
#pragma unroll
    for (int j = 0; j < 4; j++)
#pragma unroll
      for (int r = 0; r < 4; r++) {
        size_t row = m0 + wm + i * 16 + lq * 4 + r;
        int col = n0 + wn + j * 16 + lr;
        outp[row * 1024 + col] = resid[row * 1024 + col] + acc[i][j][r];
      }
}

// ---------------------------------------------------------------------------
// Flash attention, split-bf16, 32x32x16 MFMA, no running max (Q pre-scaled
// into exp2 domain; scores bounded). Block = 128 q x 1 head, 4 waves x 32 q.
// K/Vt staged via gld16 with XOR row-group swizzle. P stored as packed
// (hi|lo<<16) u32 rows of stride 68 dwords: writes hit 32 distinct banks;
// b128 reads land exactly 4 touches/bank (conflict-free by enumeration).
// ---------------------------------------------------------------------------
__global__ __launch_bounds__(256, 2) void attn_fused(
    const bf16* __restrict__ qh, const bf16* __restrict__ ql,
    const bf16* __restrict__ kh, const bf16* __restrict__ kl,
    const bf16* __restrict__ vth, const bf16* __restrict__ vtl,
    bf16* __restrict__ oh, bf16* __restrict__ ol) {
  const int S = 2048, D = 1024;
  int qt = 15 - blockIdx.y;            // heavy q-tiles first
  int hb = blockIdx.x;
  int head = hb & 15, b = hb >> 4;
  int qb = qt * 128;
  int t = threadIdx.x, lane = t & 63, w = t >> 6;
  int l31 = lane & 31, l5 = lane >> 5;
  int base = b * S, hcol = head * 64;

  __shared__ __align__(16) bf16 Kh_s[4096], Kl_s[4096];   // [key64][d64] swz
  __shared__ __align__(16) bf16 Vh_s[4096], Vl_s[4096];   // [d64][key64] swz
  __shared__ __align__(16) uint32_t Pp[4][32 * 68];       // [w][q32][key64+pad]

  // Q A-frags (32x32x16: m=lane&31=q, k chunk c: d = 16c + l5*8 + j)
  bf16x8 qfh[4], qfl[4];
  {
    const bf16* p1 = qh + (size_t)(base + qb + w * 32 + l31) * D + hcol + l5 * 8;
    const bf16* p2 = ql + (size_t)(base + qb + w * 32 + l31) * D + hcol + l5 * 8;
#pragma unroll
    for (int c = 0; c < 4; c++) {
      qfh[c] = *(const bf16x8*)(p1 + 16 * c);
      qfl[c] = *(const bf16x8*)(p2 + 16 * c);
    }
  }
  f32x16 O0, O1;
  float lrow[16];
#pragma unroll
  for (int r = 0; r < 16; r++) { O0[r] = 0.f; O1[r] = 0.f; lrow[r] = 0.f; }

  // staging: slot s in {t, t+256}: row = s>>3 (r1 = r0+32, same &7), phys
  // group p = t&7, data group g = p ^ (row&7)
  int r0 = t >> 3, p0 = t & 7;
  int r1 = 32 + r0;
  int g0 = p0 ^ (r0 & 7);
  const bf16* k0hp = kh + (size_t)(base + r0) * D + hcol + g0 * 8;
  const bf16* k1hp = kh + (size_t)(base + r1) * D + hcol + g0 * 8;
  const bf16* k0lp = kl + (size_t)(base + r0) * D + hcol + g0 * 8;
  const bf16* k1lp = kl + (size_t)(base + r1) * D + hcol + g0 * 8;
  const bf16* v0hp = vth + (size_t)(hb * 64 + r0) * 2048 + g0 * 8;
  const bf16* v1hp = vth + (size_t)(hb * 64 + r1) * 2048 + g0 * 8;
  const bf16* v0lp = vtl + (size_t)(hb * 64 + r0) * 2048 + g0 * 8;
  const bf16* v1lp = vtl + (size_t)(hb * 64 + r1) * 2048 + g0 * 8;

  int qwmin = qb + w * 32;

  for (int kt = 0; kt <= qb + 64; kt += 64) {
    __syncthreads();
    gld16(&Kh_s[t * 8], k0hp + (size_t)kt * D);
    gld16(&Kh_s[2048 + t * 8], k1hp + (size_t)kt * D);
    gld16(&Kl_s[t * 8], k0lp + (size_t)kt * D);
    gld16(&Kl_s[2048 + t * 8], k1lp + (size_t)kt * D);
    gld16(&Vh_s[t * 8], v0hp + kt);
    gld16(&Vh_s[2048 + t * 8], v1hp + kt);
    gld16(&Vl_s[t * 8], v0lp + kt);
    gld16(&Vl_s[2048 + t * 8], v1lp + kt);
    __syncthreads();
    if (kt > qwmin + 31) continue;      // wave fully masked this tile
    bool mask0 = (kt + 31 > qwmin);
    bool skip1 = (kt + 32 > qwmin + 31);  // upper 32 keys fully masked
    bool mask1 = (kt + 63 > qwmin);
    // ---- QK^T per 32-key tile ----
#pragma unroll
    for (int ktile = 0; ktile < 2; ktile++) {
      if (ktile == 1 && skip1) break;
      int keyr = ktile * 32 + l31;
      f32x16 sc;
#pragma unroll
      for (int r = 0; r < 16; r++) sc[r] = 0.f;
#pragma unroll
      for (int c = 0; c < 4; c++) {
        int dg = ((2 * c + l5) ^ (keyr & 7)) * 8;
        bf16x8 kv = *(const bf16x8*)&Kh_s[keyr * 64 + dg];
        bf16x8 km = *(const bf16x8*)&Kl_s[keyr * 64 + dg];
        sc = MFMA32(qfh[c], kv, sc);
        sc = MFMA32(qfl[c], kv, sc);
        sc = MFMA32(qfh[c], km, sc);
      }
      bool m = ktile ? mask1 : mask0;
      int keyg = kt + keyr;
      uint32_t* prow = &Pp[w][ktile * 32 + l31];
#pragma unroll
      for (int r = 0; r < 16; r++) {
        int qlocal = (r & 3) + 8 * (r >> 2) + 4 * l5;
        float sv = sc[r];
        if (m && keyg > qwmin + qlocal) sv = -30000.f;
        float pv = __builtin_amdgcn_exp2f(sv);
        lrow[r] += pv;
        prow[qlocal * 68] = pack_hilo(pv);
      }
    }
    // ---- PV: A=P (unpacked from Pp), B=V^T ----
#pragma unroll
    for (int c = 0; c < 4; c++) {
      if (skip1 && c >= 2) break;
      const uint32_t* pr = &Pp[w][l31 * 68 + 16 * c + l5 * 8];
      uint32_t pd[8];
      *(uint4*)&pd[0] = *(const uint4*)&pr[0];
      *(uint4*)&pd[4] = *(const uint4*)&pr[4];
      union { uint32_t u[4]; bf16x8 v; } ph_, pl_;
#pragma unroll
      for (int i = 0; i < 4; i++) {
        ph_.u[i] = __builtin_amdgcn_perm(pd[2 * i + 1], pd[2 * i], 0x05040100u);
        pl_.u[i] = __builtin_amdgcn_perm(pd[2 * i + 1], pd[2 * i], 0x07060302u);
      }
#pragma unroll
      for (int dtile = 0; dtile < 2; dtile++) {
        int d = dtile * 32 + l31;
        int kg = ((2 * c + l5) ^ (d & 7)) * 8;
        bf16x8 vb = *(const bf16x8*)&Vh_s[d * 64 + kg];
        bf16x8 vm = *(const bf16x8*)&Vl_s[d * 64 + kg];
        if (dtile == 0) {
          O0 = MFMA32(ph_.v, vb, O0);
          O0 = MFMA32(pl_.v, vb, O0);
          O0 = MFMA32(ph_.v, vm, O0);
        } else {
          O1 = MFMA32(ph_.v, vb, O1);
          O1 = MFMA32(pl_.v, vb, O1);
          O1 = MFMA32(ph_.v, vm, O1);
        }
      }
    }
  }
  // ---- epilogue: reduce l across the 32 key-lanes of each half ----
#pragma unroll
  for (int r = 0; r < 16; r++) {
    float l = lrow[r];
    l += __shfl_xor(l, 1); l += __shfl_xor(l, 2); l += __shfl_xor(l, 4);
    l += __shfl_xor(l, 8); l += __shfl_xor(l, 16);
    float linv = 1.f / l;
    int qlocal = (r & 3) + 8 * (r >> 2) + 4 * l5;
    size_t tok = (size_t)(base + qb + w * 32 + qlocal);
    float v0 = O0[r] * linv;
    float v1 = O1[r] * linv;
    bf16 h0 = (bf16)v0, h1 = (bf16)v1;
    oh[tok * D + hcol + l31] = h0;
    ol[tok * D + hcol + l31] = (bf16)(v0 - (float)h0);
    oh[tok * D + hcol + 32 + l31] = h1;
    ol[tok * D + hcol + 32 + l31] = (bf16)(v1 - (float)h1);
  }
}

// ---------------------------------------------------------------------------
// Routed expert GEMM (plain bf16): gather via tlist, atomicAdd scatter.
// ---------------------------------------------------------------------------
__global__ __launch_bounds__(256, 2) void gemm_moe(
    const bf16* __restrict__ A, const bf16* __restrict__ W,
    const int* __restrict__ tlist, const float* __restrict__ glist,
    const int* __restrict__ cnt, float* __restrict__ outp) {
  int e = blockIdx.z;
  int count = cnt[e];
  int m0 = blockIdx.y * 128;
  if (m0 >= count) return;
  int n0 = blockIdx.x * 128;
  const int* tl = tlist + e * 4096;
  const bf16* B = W + (size_t)e * 1024 * 1024;
  __shared__ __align__(16) bf16 As[4096], Bs[4096];
  int t = threadIdx.x, lane = t & 63, w = t >> 6;
  int i0 = t, i1 = t + 256;
  int ra = tl[m0 + (i0 >> 2)], rb = tl[m0 + (i1 >> 2)];
  const bf16* a0 = A + (size_t)ra * 1024 + (i0 & 3) * 8;
  const bf16* a1 = A + (size_t)rb * 1024 + (i1 & 3) * 8;
  const bf16* b0 = B + (size_t)(n0 + (i0 >> 2)) * 1024 + (i0 & 3) * 8;
  const bf16* b1 = B + (size_t)(n0 + (i1 >> 2)) * 1024 + (i1 & 3) * 8;
  int wm = (w >> 1) * 64, wn = (w & 1) * 64, lr = lane & 15, lq = lane >> 4;
  f32x4 acc[4][4];
#pragma unroll
  for (int i = 0; i < 4; i++)
#pragma unroll
    for (int j = 0; j < 4; j++) acc[i][j] = (f32x4){0.f, 0.f, 0.f, 0.f};
  for (int k0 = 0; k0 < 1024; k0 += 32) {
    __syncthreads();
    gld16(&As[i0 * 8], a0 + k0); gld16(&As[i1 * 8], a1 + k0);
    gld16(&Bs[i0 * 8], b0 + k0); gld16(&Bs[i1 * 8], b1 + k0);
    __syncthreads();
    bf16x8 af[4], bfr[4];
#pragma unroll
    for (int i = 0; i < 4; i++) {
      af[i] = *(const bf16x8*)&As[(wm + i * 16 + lr) * 32 + lq * 8];
      bfr[i] = *(const bf16x8*)&Bs[(wn + i * 16 + lr) * 32 + lq * 8];
    }
#pragma unroll
    for (int i = 0; i < 4; i++)
#pragma unroll
      for (int j = 0; j < 4; j++) acc[i][j] = MFMA(af[i], bfr[j], acc[i][j]);
  }
#pragma unroll
  for (int i = 0; i < 4; i++)
#pragma unroll
    for (int r = 0; r < 4; r++) {
      int slot = m0 + wm + i * 16 + lq * 4 + r;
      if (slot < count) {
        int tok = tl[slot];
        float gte = glist[e * 4096 + slot];
#pragma unroll
        for (int j = 0; j < 4; j++) {
          int col = n0 + wn + j * 16 + lr;
          atomicAdd(&outp[(size_t)tok * 1024 + col], gte * acc[i][j][r]);
        }
      }
    }
}

// ---------------------------------------------------------------------------
extern "C" void kernel_launch(void* const* d_in, const int* in_sizes, int n_in,
                              void* d_out, int out_size, void* d_ws, size_t ws_size,
                              hipStream_t stream) {
  (void)in_sizes; (void)n_in; (void)out_size; (void)ws_size;
  const float* x    = (const float*)d_in[0];
  const float* wq   = (const float*)d_in[1];
  const float* wk   = (const float*)d_in[2];
  const float* wv   = (const float*)d_in[3];
  const float* wo   = (const float*)d_in[4];
  const float* ln1g = (const float*)d_in[5];
  const float* ln1b = (const float*)d_in[6];
  const float* ln2g = (const float*)d_in[7];
  const float* ln2b = (const float*)d_in[8];
  const float* rw   = (const float*)d_in[9];
  const float* expw = (const float*)d_in[10];
  float* out = (float*)d_out;

  char* p = (char*)d_ws;
  auto take = [&](size_t bytes) -> char* {
    char* r = p;
    p += (bytes + 255) & ~(size_t)255;
    return r;
  };
  const size_t ND2 = 4096ull * 1024 * 2;  // bf16 [tokens][D]
  const size_t WD2 = 1024ull * 1024 * 2;  // bf16 [D][D]
  bf16* h_hi = (bf16*)take(ND2); bf16* h_lo = (bf16*)take(ND2);
  bf16* wqh = (bf16*)take(WD2); bf16* wql = (bf16*)take(WD2);
  bf16* wkh = (bf16*)take(WD2); bf16* wkl = (bf16*)take(WD2);
  bf16* wvh = (bf16*)take(WD2); bf16* wvl = (bf16*)take(WD2);
  bf16* woh = (bf16*)take(WD2); bf16* wol = (bf16*)take(WD2);
  bf16* q_hi = (bf16*)take(ND2); bf16* q_lo = (bf16*)take(ND2);
  bf16* k_hi = (bf16*)take(ND2); bf16* k_lo = (bf16*)take(ND2);
  bf16* vt_hi = (bf16*)take(ND2); bf16* vt_lo = (bf16*)take(ND2);
  bf16* a_hi = (bf16*)take(ND2); bf16* a_lo = (bf16*)take(ND2);
  bf16* h2h  = (bf16*)take(ND2);
  bf16* ewh  = (bf16*)take(8ull * 1024 * 1024 * 2);
  int*   tlist  = (int*)take(8ull * 4096 * 4);
  float* glist  = (float*)take(8ull * 4096 * 4);
  int*   cnt    = (int*)take(64);
  int*   reid   = (int*)take(4096 * 4);
  float2* rg    = (float2*)take(4096 * 8);

  // 1: weight prep (all conversions fused)
  prep_weights<<<12288, 256, 0, stream>>>(wq, wk, wv, wo, expw, wqh, wql, wkh,
                                          wkl, wvh, wvl, woh, wol, ewh);
  // 2: LN1
  ln_split<<<4096, 256, 0, stream>>>(x, ln1g, ln1b, h_hi, h_lo);
  // 3: QKV projection (V written transposed)
  gemm_qkv<<<dim3(8, 32, 3), 256, 0, stream>>>(h_hi, h_lo, wqh, wql, wkh, wkl,
                                               wvh, wvl, q_hi, q_lo, k_hi, k_lo,
                                               vt_hi, vt_lo);
  // 4: attention
  attn_fused<<<dim3(32, 16), 256, 0, stream>>>(q_hi, q_lo, k_hi, k_lo, vt_hi,
                                               vt_lo, a_hi, a_lo);
  // 5: WO + residual
  gemm_wo<<<dim3(8, 32), 256, 0, stream>>>(a_hi, a_lo, woh, wol, x, out);
  // 6: LN2 + router (fused, no atomics)
  ln2route<<<4096, 256, 0, stream>>>(out, ln2g, ln2b, rw, h2h, reid, rg);
  // 7: per-expert list compaction
  build_lists<<<8, 256, 0, stream>>>(reid, rg, tlist, glist, cnt);
  // 8: routed expert GEMM
  gemm_moe<<<dim3(8, 32, 8), 256, 0, stream>>>(h2h, ewh, tlist, glist, cnt,
                                               out);
}